// Round 8
// baseline (437.557 us; speedup 1.0000x reference)
//
#include <hip/hip_runtime.h>
#include <cstdint>
#include <cstddef>

#define NN 10000
#define NE 160000
#define ET (NE + NN)          // edges + self loops
#define FIN 2000
#define MPAD 10112            // 158 * 64
#define KPAD 2048
#define NPAD 896              // 7 * 128 (768 gat1 cols + 64 skip + 64 pad)

typedef __bf16 bf16x8 __attribute__((ext_vector_type(8)));
typedef __bf16 bf16x4 __attribute__((ext_vector_type(4)));
typedef float  f32x4  __attribute__((ext_vector_type(4)));

#define GLL(src, dst) __builtin_amdgcn_global_load_lds( \
    (const __attribute__((address_space(1))) void*)(src), \
    (__attribute__((address_space(3))) void*)(dst), 16, 0, 0)

// ---------------------------------------------------------------------------
// CSR build
// ---------------------------------------------------------------------------
__device__ __forceinline__ void edge_sd(const int* ei, int e, int& s, int& d) {
    if (e < NE) { s = ei[e]; d = ei[NE + e]; }
    else        { s = e - NE; d = e - NE; }
}

// exclusive scan over deg -> rowstart[0..NN]; also dinv = deg^-1/2
// (round-16: 1024 threads)
__global__ __launch_bounds__(1024)
void scan_kernel(const int* deg, int* rowstart, float* dinv) {
    __shared__ int wsum[16];
    const int T = 1024;
    int chunk = (NN + T - 1) / T;        // 10
    int t = threadIdx.x;
    int begin = t * chunk;
    int end = begin + chunk; if (end > NN) end = NN;
    if (begin > NN) begin = NN;
    int s = 0;
    for (int i = begin; i < end; i++) s += deg[i];
    int inc = s;
#pragma unroll
    for (int off = 1; off < 64; off <<= 1) {
        int u = __shfl_up(inc, off);
        if ((t & 63) >= off) inc += u;
    }
    if ((t & 63) == 63) wsum[t >> 6] = inc;
    __syncthreads();
    int woff = 0;
    for (int wv = 0; wv < (t >> 6); wv++) woff += wsum[wv];
    int run = woff + inc - s;            // exclusive prefix for this thread
    for (int i = begin; i < end; i++) {
        rowstart[i] = run; run += deg[i];
        int dg = deg[i];
        dinv[i] = dg > 0 ? rsqrtf((float)dg) : 0.f;
    }
    if (end == NN) rowstart[NN] = run;
}

__global__ void scatter_kernel(const int* ei, const int* rowstart, int* cursor,
                               int* csr_src) {
    int e = blockIdx.x * blockDim.x + threadIdx.x;
    if (e >= ET) return;
    int s, d; edge_sd(ei, e, s, d);
    int pos = atomicAdd(&cursor[d], 1);
    csr_src[rowstart[d] + pos] = s;
}

// ---------------------------------------------------------------------------
// Weight conversion + degree count. Round-17: xb branch REMOVED — gemm1 now
// GLL-stages A directly from f32 x (f32 in LDS, cvt at the ds_read).
// wt chunk: ((ct*32 + ks)*8 + p)*128 + r ; w2t chunk: (ct*16 + p)*128 + r
// wgcn1s chunk: p*128 + r (p 0..15) ; wgcn2s chunk: p*64 + r (p 0..15)
// ---------------------------------------------------------------------------
#define NW1 (NPAD * KPAD / 8)                 // 229376
#define NWT (NW1 + 512 * 128 / 8)             // 237568
#define NWT2 (NWT + 2048 + 1024)              // + wgcn1s + wgcn2s
#define WBLK ((NWT2 + 255) / 256)
#define EB 665                                 // ceil(ET/256)
__global__ void conv_kernel(const float* __restrict__ Wg, const float* __restrict__ Ws,
                            const float* __restrict__ W2,
                            const float* __restrict__ Wg1, const float* __restrict__ Wg2,
                            __bf16* __restrict__ wt, __bf16* __restrict__ w2t,
                            __bf16* __restrict__ wgcn1s, __bf16* __restrict__ wgcn2s,
                            const int* __restrict__ ei, int* __restrict__ deg) {
    int bid = blockIdx.x;
    int tid = threadIdx.x;
    if (bid < WBLK) {
        int g = bid * 256 + tid;
        if (g < NW1) {
            int r = g & 127, p = (g >> 7) & 7, ks = (g >> 10) & 31, ct = g >> 15;
            int n = ct * 128 + r;
            int k0 = ks * 64 + p * 8;
            bf16x8 o;
#pragma unroll
            for (int j = 0; j < 8; j++) {
                int k = k0 + j;
                float v = 0.f;
                if (k < FIN) {
                    if (n < 768)      v = Wg[(size_t)k * 768 + n];
                    else if (n < 832) v = Ws[(size_t)k * 64 + (n - 768)];
                }
                o[j] = (__bf16)v;
            }
            *(bf16x8*)(wt + (size_t)g * 8) = o;
        } else if (g < NWT) {
            int g2 = g - NW1;
            int c = g2 & 2047;
            int ct = g2 >> 11;
            int p = c >> 7, r = c & 127;
            int n = ct * 128 + r;
            int k0 = p * 8;
            bf16x8 o;
#pragma unroll
            for (int j = 0; j < 8; j++)
                o[j] = (__bf16)W2[(size_t)(k0 + j) * 512 + n];
            *(bf16x8*)(w2t + (size_t)g2 * 8) = o;
        } else if (g < NWT + 2048) {
            int g3 = g - NWT;
            int p = g3 >> 7, r = g3 & 127;
            bf16x8 o;
#pragma unroll
            for (int j = 0; j < 8; j++)
                o[j] = (__bf16)Wg1[(size_t)(p * 8 + j) * 128 + r];
            *(bf16x8*)(wgcn1s + (size_t)g3 * 8) = o;
        } else if (g < NWT2) {
            int g4 = g - NWT - 2048;
            int p = g4 >> 6, r = g4 & 63;
            bf16x8 o;
#pragma unroll
            for (int j = 0; j < 8; j++)
                o[j] = (__bf16)Wg2[(size_t)(p * 8 + j) * 64 + r];
            *(bf16x8*)(wgcn2s + (size_t)g4 * 8) = o;
        }
    } else {
        int e = (bid - WBLK) * 256 + tid;
        if (e < ET) {
            int s, d; edge_sd(ei, e, s, d);
            atomicAdd(&deg[d], 1);
        }
    }
}

// ---------------------------------------------------------------------------
// MFMA GEMM 1: x(f32) @ wt^T -> h1b bf16[NN,768], skippre f32[NN,64], + fused
// alpha1. 128M x 128N block, 8 waves (32x64, 4x2), BK=64, 512 threads,
// 2-barrier structure (verified plateau schedule).
// Round-17: A is GLL-staged DIRECTLY from f32 x (not the round-5 reg-staging):
//   LDS layout Asf[row][64 f32] (32 KB). Each GLL: 16 consecutive lanes cover
//   one row's 256 B contiguous K-slice (full granule use). Bank fix per rule
//   #21: LDS stays linear; the SOURCE k-slot is pre-swizzled s^=(row&7) and
//   the ds_read applies the same involution -> ~2-way (free) conflicts.
//   bf16 conversion happens at the LDS->reg read (VALU was 16% idle).
//   K-tail needs no guard: wt is zero-padded for k>=FIN, so A tail garbage
//   (finite, clamped in-bounds rows) is nullified by B zeros.
// Kills conv's xb transpose (1264 blocks) + 82 MB of HBM round-trip.
// ---------------------------------------------------------------------------
__global__ __launch_bounds__(512)
void mfma_gemm1_kernel(const float* __restrict__ x, const __bf16* __restrict__ wt,
                       const float* __restrict__ a_src1, const float* __restrict__ a_dst1,
                       __bf16* __restrict__ h1b, float* __restrict__ skippre,
                       float* __restrict__ asrc, float* __restrict__ adst) {
    __shared__ float  Asf[8192];   // 128 rows x 64 f32 (32 KB), k-slot swizzled
    __shared__ __bf16 Bs[8192];    // 8 planes x 128 rows x 8 (16 KB)
    __shared__ float sA[128], sD[128];
    __shared__ float asd[256];
    int b = blockIdx.x;
    int xcd = b & 7, j = b >> 3;
    int jq = j / 7;
    int rt = xcd + 8 * jq;            // same-rt blocks share an XCD (A-row L2 reuse)
    int ct = j - 7 * jq;
    if (rt >= MPAD / 128) return;     // 79 row tiles
    const int bi = rt * 128;
    const int bn = ct * 128;

    const int tid = threadIdx.x;
    const int lane = tid & 63;
    const int w = tid >> 6;           // 0..7
    const int wm = w >> 1;            // 0..3 : 32-row band
    const int wn = w & 1;             // 0..1 : 64-col half
    const int q = lane >> 4, m16 = lane & 15;

    if (tid < 128) { sA[tid] = 0.f; sD[tid] = 0.f; }
    if (ct < 6) {
        if (tid < 128)      asd[tid] = a_src1[ct * 128 + tid];
        else if (tid < 256) asd[tid] = a_dst1[ct * 128 + (tid - 128)];
    }

    f32x4 acc[2][4] = {};

    for (int ks = 0; ks < KPAD / 64; ks++) {
        // ---- A: GLL from f32 x. seg covers 4 rows x 16 k-slots. ----
#pragma unroll
        for (int i = 0; i < 4; i++) {
            int seg = i * 8 + w;                   // 0..31
            int row = seg * 4 + (q & 3);           // q = lane>>4 : 0..3
            int grow = bi + row; if (grow > NN - 1) grow = NN - 1;  // clamp
            int sl = m16 ^ (row & 7);              // pre-swizzled k-slot
            GLL(x + (size_t)grow * FIN + ks * 64 + sl * 4,
                Asf + seg * 256);                  // HW appends lane*16B
        }
        // ---- B: GLL from pre-swizzled bf16 wt ----
        const size_t slabB = ((size_t)ct * 32 + ks) * 1024;
#pragma unroll
        for (int i = 0; i < 2; i++) {
            int seg = i * 8 + w;                   // 0..15 = p*2 + half
            GLL(wt + (slabB + seg * 64 + lane) * 8, Bs + seg * 512);
        }
        __syncthreads();

#pragma unroll
        for (int kk = 0; kk < 2; kk++) {
            const int pb = kk * 4 + q;
            bf16x8 af[2], bfr[4];
#pragma unroll
            for (int mt = 0; mt < 2; mt++) {
                int rowm = wm * 32 + mt * 16 + m16;
                int rb = rowm & 7;
                f32x4 a0 = *(const f32x4*)(Asf + rowm * 64 + (((pb * 2)     ^ rb) << 2));
                f32x4 a1 = *(const f32x4*)(Asf + rowm * 64 + (((pb * 2 + 1) ^ rb) << 2));
                bf16x8 t;
                t[0] = (__bf16)a0[0]; t[1] = (__bf16)a0[1];
                t[2] = (__bf16)a0[2]; t[3] = (__bf16)a0[3];
                t[4] = (__bf16)a1[0]; t[5] = (__bf16)a1[1];
                t[6] = (__bf16)a1[2]; t[7] = (__bf16)a1[3];
                af[mt] = t;
            }
#pragma unroll
            for (int nt = 0; nt < 4; nt++)
                bfr[nt] = *(const bf16x8*)(Bs + (pb * 128 + wn * 64 + nt * 16 + m16) * 8);
#pragma unroll
            for (int mt = 0; mt < 2; mt++)
#pragma unroll
                for (int nt = 0; nt < 4; nt++)
                    acc[mt][nt] = __builtin_amdgcn_mfma_f32_16x16x32_bf16(af[mt], bfr[nt], acc[mt][nt], 0, 0, 0);
        }
        __syncthreads();
    }

#pragma unroll
    for (int mt = 0; mt < 2; mt++) {
#pragma unroll
        for (int r = 0; r < 4; r++) {
            int rowl = wm * 32 + mt * 16 + q * 4 + r;
            int row = bi + rowl;
            float ps = 0.f, pd = 0.f;
#pragma unroll
            for (int nt = 0; nt < 4; nt++) {
                int coll = wn * 64 + nt * 16 + m16;
                int col = bn + coll;
                float v = acc[mt][nt][r];
                if (ct < 6) { ps += v * asd[coll]; pd += v * asd[128 + coll]; }
                if (row < NN) {
                    if (col < 768)      h1b[(size_t)row * 768 + col] = (__bf16)v;
                    else if (col < 832) skippre[(size_t)row * 64 + (col - 768)] = v;
                }
            }
            if (ct < 6) {
#pragma unroll
                for (int off = 1; off < 16; off <<= 1) {
                    ps += __shfl_xor(ps, off);
                    pd += __shfl_xor(pd, off);
                }
                if (m16 == 0) { atomicAdd(&sA[rowl], ps); atomicAdd(&sD[rowl], pd); }
            }
        }
    }
    if (ct < 6) {
        __syncthreads();
        if (tid < 128) {
            int row = bi + tid;
            if (row < NN) { asrc[row * 6 + ct] = sA[tid]; adst[row * 6 + ct] = sD[tid]; }
        }
    }
}

// ---------------------------------------------------------------------------
// MFMA GEMM 2: x1gcnb(swizzled)[MPAD,128] @ w2t(swizzled)[512,128]^T -> h2b
// bf16[NN,512], + fused alpha2. 64x128 block, 4 waves (32x64), BK=64, 256 thr.
// ---------------------------------------------------------------------------
__global__ __launch_bounds__(256)
void mfma_gemm2_kernel(const __bf16* __restrict__ A, const __bf16* __restrict__ B,
                       const float* __restrict__ a_src2, const float* __restrict__ a_dst2,
                       __bf16* __restrict__ h2b,
                       float* __restrict__ asrc, float* __restrict__ adst) {
    __shared__ __bf16 As[4096];
    __shared__ __bf16 Bs[8192];
    __shared__ float sA[64], sD[64];
    __shared__ float asd[256];
    const int rt = blockIdx.y, ct = blockIdx.x;
    const int bi = rt * 64, bn = ct * 128;
    const int tid = threadIdx.x, lane = tid & 63, w = tid >> 6;
    const int wm = w >> 1, wn = w & 1;
    const int q = lane >> 4, m16 = lane & 15;

    if (tid < 64) { sA[tid] = 0.f; sD[tid] = 0.f; }
    if (tid < 128) asd[tid] = a_src2[ct * 128 + tid];
    else           asd[tid] = a_dst2[ct * 128 + (tid - 128)];

    f32x4 acc[2][4] = {};

    for (int ks = 0; ks < 2; ks++) {
        const size_t slabA = (size_t)rt * 1024 + ks * 512;
        const size_t slabB = (size_t)ct * 2048 + ks * 1024;
#pragma unroll
        for (int i = 0; i < 2; i++) {
            int seg = i * 4 + w;
            GLL(A + (slabA + seg * 64 + lane) * 8, As + seg * 512);
        }
#pragma unroll
        for (int i = 0; i < 4; i++) {
            int seg = i * 4 + w;
            GLL(B + (slabB + seg * 64 + lane) * 8, Bs + seg * 512);
        }
        __syncthreads();

#pragma unroll
        for (int kk = 0; kk < 2; kk++) {
            const int pb = kk * 4 + q;
            bf16x8 af[2], bfr[4];
#pragma unroll
            for (int mt = 0; mt < 2; mt++)
                af[mt] = *(const bf16x8*)(As + (pb * 64 + wm * 32 + mt * 16 + m16) * 8);
#pragma unroll
            for (int nt = 0; nt < 4; nt++)
                bfr[nt] = *(const bf16x8*)(Bs + (pb * 128 + wn * 64 + nt * 16 + m16) * 8);
#pragma unroll
            for (int mt = 0; mt < 2; mt++)
#pragma unroll
                for (int nt = 0; nt < 4; nt++)
                    acc[mt][nt] = __builtin_amdgcn_mfma_f32_16x16x32_bf16(af[mt], bfr[nt], acc[mt][nt], 0, 0, 0);
        }
        __syncthreads();
    }

#pragma unroll
    for (int mt = 0; mt < 2; mt++) {
#pragma unroll
        for (int r = 0; r < 4; r++) {
            int rowl = wm * 32 + mt * 16 + q * 4 + r;
            int row = bi + rowl;
            float ps = 0.f, pd = 0.f;
#pragma unroll
            for (int nt = 0; nt < 4; nt++) {
                int coll = wn * 64 + nt * 16 + m16;
                float v = acc[mt][nt][r];
                ps += v * asd[coll]; pd += v * asd[128 + coll];
                if (row < NN) h2b[(size_t)row * 512 + bn + coll] = (__bf16)v;
            }
#pragma unroll
            for (int off = 1; off < 16; off <<= 1) {
                ps += __shfl_xor(ps, off);
                pd += __shfl_xor(pd, off);
            }
            if (m16 == 0) { atomicAdd(&sA[rowl], ps); atomicAdd(&sD[rowl], pd); }
        }
    }
    __syncthreads();
    if (tid < 64) {
        int row = bi + tid;
        if (row < NN) { asrc[row * 4 + ct] = sA[tid]; adst[row * 4 + ct] = sD[tid]; }
    }
}

// ---------------------------------------------------------------------------
// MFMA GCN GEMM: A(swizzled)[MPAD,128] @ Bs(swizzled)[NT,128]^T -> y bf16[NN,NT]
// 64M x NT block, 4 waves, BK=64 (2 iters), 256 threads. NT in {64,128}.
// ---------------------------------------------------------------------------
template<int NT>
__global__ __launch_bounds__(256)
void mfma_gcn_kernel(const __bf16* __restrict__ A, const __bf16* __restrict__ B,
                     __bf16* __restrict__ Cb) {
    __shared__ __bf16 As[4096];
    __shared__ __bf16 Bs[NT * 64];      // 8 planes x NT rows x 8
    const int rt = blockIdx.x;
    const int bi = rt * 64;
    const int tid = threadIdx.x, lane = tid & 63, w = tid >> 6;
    const int q = lane >> 4, m16 = lane & 15;
    constexpr int MT = (NT == 128) ? 2 : 1;
    constexpr int MSPAN = (NT == 128) ? 32 : 16;
    const int wm = (NT == 128) ? (w >> 1) : w;
    const int wn = (NT == 128) ? (w & 1) : 0;

    f32x4 acc[MT][4] = {};

    for (int ks = 0; ks < 2; ks++) {
        const size_t slabA = (size_t)rt * 1024 + ks * 512;
        const size_t slabB = (size_t)ks * (NT * 8);
#pragma unroll
        for (int i = 0; i < 2; i++) {
            int seg = i * 4 + w;
            GLL(A + (slabA + seg * 64 + lane) * 8, As + seg * 512);
        }
#pragma unroll
        for (int i = 0; i < NT / 32; i++) {
            int seg = i * 4 + w;
            GLL(B + (slabB + (size_t)seg * 64 + lane) * 8, Bs + seg * 512);
        }
        __syncthreads();

#pragma unroll
        for (int kk = 0; kk < 2; kk++) {
            const int pb = kk * 4 + q;
            bf16x8 af[MT], bfr[4];
#pragma unroll
            for (int mt = 0; mt < MT; mt++)
                af[mt] = *(const bf16x8*)(As + (pb * 64 + wm * MSPAN + mt * 16 + m16) * 8);
#pragma unroll
            for (int nt = 0; nt < 4; nt++)
                bfr[nt] = *(const bf16x8*)(Bs + (pb * NT + wn * 64 + nt * 16 + m16) * 8);
#pragma unroll
            for (int mt = 0; mt < MT; mt++)
#pragma unroll
                for (int nt = 0; nt < 4; nt++)
                    acc[mt][nt] = __builtin_amdgcn_mfma_f32_16x16x32_bf16(af[mt], bfr[nt], acc[mt][nt], 0, 0, 0);
        }
        __syncthreads();
    }

#pragma unroll
    for (int mt = 0; mt < MT; mt++) {
#pragma unroll
        for (int r = 0; r < 4; r++) {
            int row = bi + wm * MSPAN + mt * 16 + q * 4 + r;
            if (row >= NN) continue;
#pragma unroll
            for (int nt = 0; nt < 4; nt++) {
                int col = wn * 64 + nt * 16 + m16;
                Cb[(size_t)row * NT + col] = (__bf16)acc[mt][nt][r];
            }
        }
    }
}

// ---------------------------------------------------------------------------
// Fused segment-softmax + aggregation + head-mean + bias + LN + ReLU.
// Round-17: T14 prefetch deepened 2 -> 4 edges/wave (named registers, not
// runtime-indexed arrays — rule #20). With mean deg ~17, 16 prefetched edges
// cover most blocks' entire phase-2 gather under phase-1 latency.
// ---------------------------------------------------------------------------
template<int H>
__global__ void gat_agg_kernel(const __bf16* __restrict__ hb,
                               const float* __restrict__ asrc,
                               const float* __restrict__ adst,
                               const int* __restrict__ rowstart,
                               const int* __restrict__ csr_src,
                               const float* __restrict__ bias,
                               const float* __restrict__ gamma,
                               const float* __restrict__ beta,
                               __bf16* __restrict__ outs) {
    constexpr int CH = H * 128;
    constexpr int CAP = 128;
    int n = blockIdx.x;
    int t = threadIdx.x;
    int w = t >> 6, l = t & 63;
    __shared__ float invden[H];
    __shared__ float denp[256];
    __shared__ int   srcs[CAP];
    __shared__ float evs[CAP * H];
    __shared__ float sm[4 * CH];
    __shared__ float red[8];

    int s0 = rowstart[n];
    int deg = rowstart[n + 1] - s0;
    int degc = deg < CAP ? deg : CAP;
    float adst_n = (l < H) ? adst[n * H + l] : 0.f;   // for fallback path

    // phase 0: cooperative srcs load
    if (t < degc) srcs[t] = csr_src[s0 + t];
    __syncthreads();

    // prologue (T14): issue this wave's first FOUR h-row gathers now — they
    // depend only on srcs, so their latency overlaps all of phase 1.
    const int h0 = l >> 4;
    const int h1i = 4 + (l >> 5);
    const int i0 = w, i1 = w + 4, i2 = w + 8, i3 = w + 12;
    const bool has0 = i0 < degc, has1 = i1 < degc;
    const bool has2 = i2 < degc, has3 = i3 < degc;
    bf16x8 pg0, pg1, pg2, pg3; bf16x4 pe0, pe1, pe2, pe3;
    if (has0) {
        const __bf16* hp = hb + (size_t)srcs[i0] * CH;
        pg0 = *(const bf16x8*)(hp + l * 8);
        if (H == 6) pe0 = *(const bf16x4*)(hp + 512 + l * 4);
    }
    if (has1) {
        const __bf16* hp = hb + (size_t)srcs[i1] * CH;
        pg1 = *(const bf16x8*)(hp + l * 8);
        if (H == 6) pe1 = *(const bf16x4*)(hp + 512 + l * 4);
    }
    if (has2) {
        const __bf16* hp = hb + (size_t)srcs[i2] * CH;
        pg2 = *(const bf16x8*)(hp + l * 8);
        if (H == 6) pe2 = *(const bf16x4*)(hp + 512 + l * 4);
    }
    if (has3) {
        const __bf16* hp = hb + (size_t)srcs[i3] * CH;
        pg3 = *(const bf16x8*)(hp + l * 8);
        if (H == 6) pe3 = *(const bf16x4*)(hp + 512 + l * 4);
    }

    // phase 1: parallel over (edge, head): 8 lanes per edge, 32 edges/pass
    const int eh = t >> 3;      // edge slot within pass (0..31)
    const int hh1 = t & 7;      // head (hh1 < H active)
    float adst_h = (hh1 < H) ? adst[n * H + hh1] : 0.f;
    float dloc = 0.f;
    for (int base = 0; base < deg; base += 32) {
        int idx = base + eh;
        if (idx < deg && hh1 < H) {
            int src = (idx < CAP) ? srcs[idx] : csr_src[s0 + idx];
            float al = asrc[src * H + hh1] + adst_h;
            al = al >= 0.f ? al : 0.2f * al;
            float ev = __expf(al);
            dloc += ev;
            if (idx < CAP) evs[idx * H + hh1] = ev;
        }
    }
    denp[t] = dloc;
    __syncthreads();
    if (t < H) {
        float s = 0.f;
#pragma unroll
        for (int g = 0; g < 32; g++) s += denp[g * 8 + t];
        invden[t] = 1.f / s;
    }
    __syncthreads();

    // phase 2: weighted feature accumulation
    constexpr int NA = (H == 6) ? 12 : 8;
    float acc[NA] = {};
    // consume the preloaded edges (weights now available in evs)
    if (has0) {
        float w0 = evs[i0 * H + h0];
#pragma unroll
        for (int jj = 0; jj < 8; jj++) acc[jj] += (float)pg0[jj] * w0;
        if (H == 6) {
            float w1 = evs[i0 * H + h1i];
#pragma unroll
            for (int jj = 0; jj < 4; jj++) acc[8 + jj] += (float)pe0[jj] * w1;
        }
    }
    if (has1) {
        float w0 = evs[i1 * H + h0];
#pragma unroll
        for (int jj = 0; jj < 8; jj++) acc[jj] += (float)pg1[jj] * w0;
        if (H == 6) {
            float w1 = evs[i1 * H + h1i];
#pragma unroll
            for (int jj = 0; jj < 4; jj++) acc[8 + jj] += (float)pe1[jj] * w1;
        }
    }
    if (has2) {
        float w0 = evs[i2 * H + h0];
#pragma unroll
        for (int jj = 0; jj < 8; jj++) acc[jj] += (float)pg2[jj] * w0;
        if (H == 6) {
            float w1 = evs[i2 * H + h1i];
#pragma unroll
            for (int jj = 0; jj < 4; jj++) acc[8 + jj] += (float)pe2[jj] * w1;
        }
    }
    if (has3) {
        float w0 = evs[i3 * H + h0];
#pragma unroll
        for (int jj = 0; jj < 8; jj++) acc[jj] += (float)pg3[jj] * w0;
        if (H == 6) {
            float w1 = evs[i3 * H + h1i];
#pragma unroll
            for (int jj = 0; jj < 4; jj++) acc[8 + jj] += (float)pe3[jj] * w1;
        }
    }
    // remaining edges from w+16, 2-edge pipelined
    int idx = w + 16;
    for (; idx + 4 < degc; idx += 8) {
        int src0 = srcs[idx], src1 = srcs[idx + 4];
        float w00 = evs[idx * H + h0];
        float w10 = evs[(idx + 4) * H + h0];
        const __bf16* hp0 = hb + (size_t)src0 * CH;
        const __bf16* hp1 = hb + (size_t)src1 * CH;
        bf16x8 g00 = *(const bf16x8*)(hp0 + l * 8);
        bf16x8 g10 = *(const bf16x8*)(hp1 + l * 8);
#pragma unroll
        for (int jj = 0; jj < 8; jj++)
            acc[jj] += (float)g00[jj] * w00 + (float)g10[jj] * w10;
        if (H == 6) {
            float w01 = evs[idx * H + h1i];
            float w11 = evs[(idx + 4) * H + h1i];
            bf16x4 g01 = *(const bf16x4*)(hp0 + 512 + l * 4);
            bf16x4 g11 = *(const bf16x4*)(hp1 + 512 + l * 4);
#pragma unroll
            for (int jj = 0; jj < 4; jj++)
                acc[8 + jj] += (float)g01[jj] * w01 + (float)g11[jj] * w11;
        }
    }
    if (idx < degc) {
        int src = srcs[idx];
        float w0 = evs[idx * H + h0];
        const __bf16* hp = hb + (size_t)src * CH;
        bf16x8 hv = *(const bf16x8*)(hp + l * 8);
#pragma unroll
        for (int jj = 0; jj < 8; jj++) acc[jj] += (float)hv[jj] * w0;
        if (H == 6) {
            float w1 = evs[idx * H + h1i];
            bf16x4 hv1 = *(const bf16x4*)(hp + 512 + l * 4);
#pragma unroll
            for (int jj = 0; jj < 4; jj++) acc[8 + jj] += (float)hv1[jj] * w1;
        }
    }
    // fallback: uncached edges (deg > CAP; effectively never for this graph)
    for (int i2f = CAP + w; i2f < deg; i2f += 4) {
        int src = csr_src[s0 + i2f];
        float ev = 0.f;
        if (l < H) {
            float al = asrc[src * H + l] + adst_n;
            al = al >= 0.f ? al : 0.2f * al;
            ev = __expf(al);
        }
        const __bf16* hp = hb + (size_t)src * CH;
        float wgt = __shfl(ev, h0);
        bf16x8 hv = *(const bf16x8*)(hp + l * 8);
#pragma unroll
        for (int jj = 0; jj < 8; jj++) acc[jj] += (float)hv[jj] * wgt;
        if (H == 6) {
            float wg1 = __shfl(ev, h1i);
            bf16x4 hv1 = *(const bf16x4*)(hp + 512 + l * 4);
#pragma unroll
            for (int jj = 0; jj < 4; jj++) acc[8 + jj] += (float)hv1[jj] * wg1;
        }
    }

    *(f32x4*)(sm + w * CH + l * 8)     = *(f32x4*)(acc);
    *(f32x4*)(sm + w * CH + l * 8 + 4) = *(f32x4*)(acc + 4);
    if (H == 6)
        *(f32x4*)(sm + w * CH + 512 + l * 4) = *(f32x4*)(acc + 8);
    __syncthreads();

    float v = 0.f;
    if (t < 128) {
#pragma unroll
        for (int hh = 0; hh < H; hh++) {
            float hsum = 0.f;
#pragma unroll
            for (int ww = 0; ww < 4; ww++) hsum += sm[ww * CH + hh * 128 + t];
            v += hsum * invden[hh];
        }
        v = v * (1.f / H) + bias[t];
    }
    float sv = (t < 128) ? v : 0.f;
    float sq = (t < 128) ? v * v : 0.f;
#pragma unroll
    for (int off = 32; off; off >>= 1) {
        sv += __shfl_down(sv, off);
        sq += __shfl_down(sq, off);
    }
    if ((t & 63) == 0) { red[w * 2] = sv; red[w * 2 + 1] = sq; }
    __syncthreads();
    float tot = red[0] + red[2] + red[4] + red[6];
    float tsq = red[1] + red[3] + red[5] + red[7];
    float mu = tot * (1.f / 128.f);
    float var = tsq * (1.f / 128.f) - mu * mu;
    float r = rsqrtf(var + 1e-5f);
    if (t < 128) {
        float o = fmaxf((v - mu) * r * gamma[t] + beta[t], 0.f);
        // MFMA-A swizzled store: n -> (rt,r), t -> (p,off)
        int rt2 = n >> 6, rr = n & 63, pp = t >> 3, off2 = t & 7;
        outs[((size_t)(rt2 * 16 + pp) * 64 + rr) * 8 + off2] = (__bf16)o;
    }
}

// ---------------------------------------------------------------------------
// per-node GCN aggregation (round-15 vectorized): LPE lanes own 8 cols each
// (16B loads), G edge-groups in flight; LDS tree-reduce across groups.
// ---------------------------------------------------------------------------
template<int C>
__global__ void gcn_agg_kernel(const __bf16* __restrict__ y,
                               const float* __restrict__ dinv,
                               const int* __restrict__ rowstart,
                               const int* __restrict__ csr_src,
                               const float* __restrict__ bias,
                               float* __restrict__ out, int coloff,
                               __bf16* __restrict__ bout) {
    constexpr int LPE = C / 8;        // lanes per edge (16 or 8)
    constexpr int G = 128 / LPE;      // edge groups in flight (8 or 16)
    __shared__ float sm[G * C];       // 4 KB
    int n = blockIdx.x;
    int t = threadIdx.x;
    int lane = t & (LPE - 1);
    int grp = t / LPE;
    float acc[8] = {};
    int s0 = rowstart[n], s1 = rowstart[n + 1];
    for (int e = s0 + grp; e < s1; e += G) {
        int src = csr_src[e];
        float dv = dinv[src];
        bf16x8 v = *(const bf16x8*)(y + (size_t)src * C + lane * 8);
#pragma unroll
        for (int j = 0; j < 8; j++) acc[j] += (float)v[j] * dv;
    }
    *(f32x4*)(sm + grp * C + lane * 8)     = *(f32x4*)(acc);
    *(f32x4*)(sm + grp * C + lane * 8 + 4) = *(f32x4*)(acc + 4);
    __syncthreads();
    if (t < C) {
        float v = 0.f;
#pragma unroll
        for (int g = 0; g < G; g++) v += sm[g * C + t];
        v = fmaxf(v * dinv[n] + bias[t], 0.f);
        out[(size_t)n * 192 + coloff + t] = v;
        if (bout) {
            int rt = n >> 6, r = n & 63, p = t >> 3, off = t & 7;
            bout[((size_t)(rt * 16 + p) * 64 + r) * 8 + off] = (__bf16)v;
        }
    }
}

// ---------------------------------------------------------------------------
// Fused: fused=relu(cat@W_fuse+b_fuse); v=fused+relu(skippre+b_skip);
// LN(v) -> 64->32->16->5 MLP. (round-15: 16 nodes/block, verified)
// ---------------------------------------------------------------------------
__global__ __launch_bounds__(256)
void fuse_final_kernel(const float* __restrict__ cat,
                       const float* __restrict__ skippre,
                       const float* __restrict__ Wf, const float* __restrict__ bfz,
                       const float* __restrict__ b_skip,
                       const float* __restrict__ g3, const float* __restrict__ be3,
                       const float* __restrict__ Wc1, const float* __restrict__ bc1,
                       const float* __restrict__ Wc2, const float* __restrict__ bc2,
                       const float* __restrict__ Wc3, const float* __restrict__ bc3,
                       float* __restrict__ out) {
    __shared__ float WfS[192 * 64];     // 48 KB
    __shared__ float catS[4][4][196];   // 12.25 KB
    __shared__ float fS[4][64], h1S[4][32], h2S[4][16];
    int tid = threadIdx.x;
    int w = tid >> 6, l = tid & 63;
#pragma unroll
    for (int i = 0; i < 12; i++) {
        int idx = (i * 256 + tid) * 4;
        *(f32x4*)(WfS + idx) = *(const f32x4*)(Wf + idx);
    }
    int n0 = blockIdx.x * 16 + w * 4;
    float sk[4];
#pragma unroll
    for (int i = 0; i < 4; i++) {
        int n = n0 + i;
        if (n < NN) {
            catS[w][i][l]       = cat[(size_t)n * 192 + l];
            catS[w][i][64 + l]  = cat[(size_t)n * 192 + 64 + l];
            catS[w][i][128 + l] = cat[(size_t)n * 192 + 128 + l];
            sk[i] = fmaxf(skippre[(size_t)n * 64 + l] + b_skip[l], 0.f);
        } else {
            sk[i] = 0.f;
        }
    }
    __syncthreads();

#pragma unroll
    for (int i = 0; i < 4; i++) {
        int n = n0 + i;
        if (n < NN) {
            float fu = bfz[l];
#pragma unroll 4
            for (int k = 0; k < 192; k++)
                fu += catS[w][i][k] * WfS[k * 64 + l];
            float v = fmaxf(fu, 0.f) + sk[i];

            float sv = v, sq = v * v;
#pragma unroll
            for (int off = 32; off; off >>= 1) {
                sv += __shfl_xor(sv, off);
                sq += __shfl_xor(sq, off);
            }
            float mu = sv * (1.f / 64.f);
            float var = sq * (1.f / 64.f) - mu * mu;
            float r = rsqrtf(var + 1e-5f);
            fS[w][l] = (v - mu) * r * g3[l] + be3[l];
            // per-wave private LDS: no __syncthreads needed between stages
            if (l < 32) {
                float a = bc1[l];
                for (int k = 0; k < 64; k++) a += fS[w][k] * Wc1[k * 32 + l];
                h1S[w][l] = fmaxf(a, 0.f);
            }
            if (l < 16) {
                float a = bc2[l];
                for (int k = 0; k < 32; k++) a += h1S[w][k] * Wc2[k * 16 + l];
                h2S[w][l] = fmaxf(a, 0.f);
            }
            if (l < 5) {
                float a = bc3[l];
                for (int k = 0; k < 16; k++) a += h2S[w][k] * Wc3[k * 5 + l];
                out[(size_t)n * 5 + l] = a;
            }
        }
    }
}

// ---------------------------------------------------------------------------
extern "C" void kernel_launch(void* const* d_in, const int* in_sizes, int n_in,
                              void* d_out, int out_size, void* d_ws, size_t ws_size,
                              hipStream_t stream) {
    const float* x      = (const float*)d_in[0];
    const int*   ei     = (const int*)d_in[1];
    const float* W_gat1 = (const float*)d_in[2];
    const float* a_src1 = (const float*)d_in[3];
    const float* a_dst1 = (const float*)d_in[4];
    const float* b_gat1 = (const float*)d_in[5];
    const float* W_gcn1 = (const float*)d_in[6];
    const float* b_gcn1 = (const float*)d_in[7];
    const float* W_gat2 = (const float*)d_in[8];
    const float* a_src2 = (const float*)d_in[9];
    const float* a_dst2 = (const float*)d_in[10];
    const float* b_gat2 = (const float*)d_in[11];
    const float* W_gcn2 = (const float*)d_in[12];
    const float* b_gcn2 = (const float*)d_in[13];
    const float* W_skip = (const float*)d_in[14];
    const float* b_skip = (const float*)d_in[15];
    const float* W_fuse = (const float*)d_in[16];
    const float* b_fuse = (const float*)d_in[17];
    const float* W_c1   = (const float*)d_in[18];
    const float* b_c1   = (const float*)d_in[19];
    const float* W_c2   = (const float*)d_in[20];
    const float* b_c2   = (const float*)d_in[21];
    const float* W_c3   = (const float*)d_in[22];
    const float* b_c3   = (const float*)d_in[23];
    const float* g1     = (const float*)d_in[24];
    const float* be1    = (const float*)d_in[25];
    const float* g2     = (const float*)d_in[26];
    const float* be2    = (const float*)d_in[27];
    const float* g3     = (const float*)d_in[28];
    const float* be3    = (const float*)d_in[29];
    float* out = (float*)d_out;

    // workspace arena
    char* p = (char*)d_ws;
    auto alloc = [&](size_t bytes) {
        char* r = p; p += (bytes + 255) & ~(size_t)255; return r;
    };
    __bf16* wt      = (__bf16*)alloc((size_t)NPAD * KPAD * 2);   // 3.7 MB  (swizzled)
    __bf16* w2t     = (__bf16*)alloc((size_t)512 * 128 * 2);     // swizzled
    __bf16* wgcn1s  = (__bf16*)alloc((size_t)128 * 128 * 2);     // swizzled
    __bf16* wgcn2s  = (__bf16*)alloc((size_t)64 * 128 * 2);      // swizzled
    __bf16* h1b     = (__bf16*)alloc((size_t)NN * 768 * 2);      // 15.4 MB
    __bf16* h2b     = (__bf16*)alloc((size_t)NN * 512 * 2);      // 10.2 MB
    __bf16* ybufb   = (__bf16*)alloc((size_t)NN * 128 * 2);      // y1 reused y2
    // three swizzled activation buffers, contiguous for a single memset
    __bf16* x1gatb  = (__bf16*)alloc((size_t)3 * MPAD * 128 * 2);
    __bf16* x1gcnb  = x1gatb + (size_t)MPAD * 128;
    __bf16* x2gatb  = x1gcnb + (size_t)MPAD * 128;
    float* asrc     = (float*)alloc((size_t)NN * 6 * 4);
    float* adst     = (float*)alloc((size_t)NN * 6 * 4);
    int*   deg      = (int*)  alloc((size_t)2 * NN * 4);         // deg | cursor
    int*   cursor   = deg + NN;
    float* dinv     = (float*)alloc((size_t)NN * 4);
    int*   rowst    = (int*)  alloc((size_t)(NN + 1) * 4);
    int*   csrc     = (int*)  alloc((size_t)ET * 4);
    float* cat      = (float*)alloc((size_t)NN * 192 * 4);
    float* skippre  = (float*)alloc((size_t)NN * 64 * 4);

    hipMemsetAsync(deg, 0, (size_t)2 * NN * 4, stream);
    hipMemsetAsync(x1gatb, 0, (size_t)3 * MPAD * 128 * 2, stream);  // pad rows

    // weight conversions + degree count (xb transpose removed, round-17)
    conv_kernel<<<WBLK + EB, 256, 0, stream>>>(
        W_gat1, W_skip, W_gat2, W_gcn1, W_gcn2,
        wt, w2t, wgcn1s, wgcn2s, ei, deg);

    // CSR by dst
    scan_kernel   <<<1, 1024, 0, stream>>>(deg, rowst, dinv);
    scatter_kernel<<<EB, 256, 0, stream>>>(ei, rowst, cursor, csrc);

    // h1 (bf16) + skippre + fused alpha1, XCD-swizzled 128x128 BK=64, 8 waves,
    // A GLL-staged direct from f32 x (round-17)
    mfma_gemm1_kernel<<<560, 512, 0, stream>>>(x, wt, a_src1, a_dst1,
                                               h1b, skippre, asrc, adst);

    // ---- GAT layer 1 (H=6) -> bf16 swizzled x1gatb ----
    gat_agg_kernel<6><<<NN, 256, 0, stream>>>(h1b, asrc, adst, rowst, csrc,
                                              b_gat1, g1, be1, x1gatb);
    // ---- GCN layer 1: y1 = x1gat @ W_gcn1 (MFMA) ----
    mfma_gcn_kernel<128><<<MPAD / 64, 256, 0, stream>>>(x1gatb, wgcn1s, ybufb);
    gcn_agg_kernel<128><<<NN, 128, 0, stream>>>(ybufb, dinv, rowst, csrc,
                                                b_gcn1, cat, 0, x1gcnb);
    // ---- GAT layer 2 (H=4): h2 + fused alpha2 (bf16 MFMA, 4 waves) ----
    mfma_gemm2_kernel<<<dim3(4, MPAD / 64), 256, 0, stream>>>(
        x1gcnb, w2t, a_src2, a_dst2, h2b, asrc, adst);
    gat_agg_kernel<4><<<NN, 256, 0, stream>>>(h2b, asrc, adst, rowst, csrc,
                                              b_gat2, g2, be2, x2gatb);
    // ---- GCN layer 2: y2 = x2gat @ W_gcn2 (MFMA) -> cat[:, 128:192] ----
    mfma_gcn_kernel<64><<<MPAD / 64, 256, 0, stream>>>(x2gatb, wgcn2s, ybufb);
    gcn_agg_kernel<64><<<NN, 128, 0, stream>>>(ybufb, dinv, rowst, csrc,
                                               b_gcn2, cat, 128, nullptr);
    // ---- fuse + final (round-15: 16 nodes/block) ----
    fuse_final_kernel<<<(NN + 15) / 16, 256, 0, stream>>>(
        cat, skippre, W_fuse, b_fuse, b_skip, g3, be3,
        W_c1, b_c1, W_c2, b_c2, W_c3, b_c3, out);
}

// Round 9
// 405.389 us; speedup vs baseline: 1.0793x; 1.0793x over previous
//
#include <hip/hip_runtime.h>
#include <cstdint>
#include <cstddef>

#define NN 10000
#define NE 160000
#define ET (NE + NN)          // edges + self loops
#define FIN 2000
#define MPAD 10112            // 158 * 64
#define KPAD 2048
#define NPAD 896              // 7 * 128 (768 gat1 cols + 64 skip + 64 pad)

typedef __bf16 bf16x8 __attribute__((ext_vector_type(8)));
typedef __bf16 bf16x4 __attribute__((ext_vector_type(4)));
typedef float  f32x4  __attribute__((ext_vector_type(4)));

#define GLL(src, dst) __builtin_amdgcn_global_load_lds( \
    (const __attribute__((address_space(1))) void*)(src), \
    (__attribute__((address_space(3))) void*)(dst), 16, 0, 0)

// ---------------------------------------------------------------------------
// CSR build
// ---------------------------------------------------------------------------
__device__ __forceinline__ void edge_sd(const int* ei, int e, int& s, int& d) {
    if (e < NE) { s = ei[e]; d = ei[NE + e]; }
    else        { s = e - NE; d = e - NE; }
}

// exclusive scan over deg -> rowstart[0..NN]; also dinv = deg^-1/2
// (round-16: 1024 threads)
__global__ __launch_bounds__(1024)
void scan_kernel(const int* deg, int* rowstart, float* dinv) {
    __shared__ int wsum[16];
    const int T = 1024;
    int chunk = (NN + T - 1) / T;        // 10
    int t = threadIdx.x;
    int begin = t * chunk;
    int end = begin + chunk; if (end > NN) end = NN;
    if (begin > NN) begin = NN;
    int s = 0;
    for (int i = begin; i < end; i++) s += deg[i];
    int inc = s;
#pragma unroll
    for (int off = 1; off < 64; off <<= 1) {
        int u = __shfl_up(inc, off);
        if ((t & 63) >= off) inc += u;
    }
    if ((t & 63) == 63) wsum[t >> 6] = inc;
    __syncthreads();
    int woff = 0;
    for (int wv = 0; wv < (t >> 6); wv++) woff += wsum[wv];
    int run = woff + inc - s;            // exclusive prefix for this thread
    for (int i = begin; i < end; i++) {
        rowstart[i] = run; run += deg[i];
        int dg = deg[i];
        dinv[i] = dg > 0 ? rsqrtf((float)dg) : 0.f;
    }
    if (end == NN) rowstart[NN] = run;
}

__global__ void scatter_kernel(const int* ei, const int* rowstart, int* cursor,
                               int* csr_src) {
    int e = blockIdx.x * blockDim.x + threadIdx.x;
    if (e >= ET) return;
    int s, d; edge_sd(ei, e, s, d);
    int pos = atomicAdd(&cursor[d], 1);
    csr_src[rowstart[d] + pos] = s;
}

// ---------------------------------------------------------------------------
// Merged conversion + degree count (round-12 verified xb transpose; restored
// after r14/r17 both proved direct-f32 A staging is 2x slower than GLL-from-
// bf16-xb — ledger closed, do not touch).
// xb chunk c = ((rt*32 + ks)*8 + p)*64 + r holds x[rt*64+r][ks*64+p*8 ..+8)
// wt chunk: ((ct*32 + ks)*8 + p)*128 + r ; w2t chunk: (ct*16 + p)*128 + r
// wgcn1s chunk: p*128 + r (p 0..15) ; wgcn2s chunk: p*64 + r (p 0..15)
// ---------------------------------------------------------------------------
#define NBX (158 * 8)
#define NW1 (NPAD * KPAD / 8)                 // 229376
#define NWT (NW1 + 512 * 128 / 8)             // 237568
#define NWT2 (NWT + 2048 + 1024)              // + wgcn1s + wgcn2s
#define WBLK ((NWT2 + 255) / 256)
#define EB 665                                 // ceil(ET/256)
__global__ void conv_kernel(const float* __restrict__ x, __bf16* __restrict__ xb,
                            const float* __restrict__ Wg, const float* __restrict__ Ws,
                            const float* __restrict__ W2,
                            const float* __restrict__ Wg1, const float* __restrict__ Wg2,
                            __bf16* __restrict__ wt, __bf16* __restrict__ w2t,
                            __bf16* __restrict__ wgcn1s, __bf16* __restrict__ wgcn2s,
                            const int* __restrict__ ei, int* __restrict__ deg) {
    __shared__ __bf16 ls[16384];   // 32 KB: 4 slabs x 8 p x 64 r x 8 (swizzled)
    int bid = blockIdx.x;
    int tid = threadIdx.x;
    if (bid < NBX) {
        int rt = bid >> 3, kb = bid & 7;       // 64-row tile, 256-k tile
        const int lane16 = tid & 15;           // k-chunk owner within row
        const int ksl = lane16 >> 2;           // slab 0..3
        const int p0 = (lane16 & 3) * 2;       // p pair {p0, p0+1}
        const int rbase = tid >> 4;            // 0..15
        const int kg0 = kb * 256 + lane16 * 16;
        const int rsw_x = (p0 & 6) ^ ksl;      // swizzle const for this thread
#pragma unroll
        for (int pass = 0; pass < 4; pass++) {
            int r = pass * 16 + rbase;
            int row = rt * 64 + r;
            bf16x8 v0, v1;
#pragma unroll
            for (int j = 0; j < 4; j++) {
                int k = kg0 + j * 4;
                f32x4 f;
                if (row < NN && k + 3 < FIN)
                    f = *(const f32x4*)(x + (size_t)row * FIN + k);
                else
                    f = (f32x4){0.f, 0.f, 0.f, 0.f};
                int o = (j & 1) * 4;
                if (j < 2) {
                    v0[o] = (__bf16)f[0]; v0[o+1] = (__bf16)f[1];
                    v0[o+2] = (__bf16)f[2]; v0[o+3] = (__bf16)f[3];
                } else {
                    v1[o] = (__bf16)f[0]; v1[o+1] = (__bf16)f[1];
                    v1[o+2] = (__bf16)f[2]; v1[o+3] = (__bf16)f[3];
                }
            }
            int rsw = r ^ rsw_x;
            *(bf16x8*)(ls + (((ksl * 8 + p0) * 64 + rsw) * 8))     = v0;
            *(bf16x8*)(ls + (((ksl * 8 + p0 + 1) * 64 + rsw) * 8)) = v1;
        }
        __syncthreads();
        size_t cbase = ((size_t)rt * 32 + kb * 4) * 512;
#pragma unroll
        for (int i = 0; i < 8; i++) {
            int g = i * 256 + tid;             // 0..2047
            int ksl2 = g >> 9, rem = g & 511;
            int p = rem >> 6, rr = rem & 63;
            int rsw = rr ^ ((p & 6) ^ ksl2);
            bf16x8 v = *(const bf16x8*)(ls + (((ksl2 * 8 + p) * 64 + rsw) * 8));
            *(bf16x8*)(xb + (cbase + (size_t)ksl2 * 512 + (p * 64 + rr)) * 8) = v;
        }
    } else if (bid < NBX + WBLK) {
        int g = (bid - NBX) * 256 + tid;
        if (g < NW1) {
            int r = g & 127, p = (g >> 7) & 7, ks = (g >> 10) & 31, ct = g >> 15;
            int n = ct * 128 + r;
            int k0 = ks * 64 + p * 8;
            bf16x8 o;
#pragma unroll
            for (int j = 0; j < 8; j++) {
                int k = k0 + j;
                float v = 0.f;
                if (k < FIN) {
                    if (n < 768)      v = Wg[(size_t)k * 768 + n];
                    else if (n < 832) v = Ws[(size_t)k * 64 + (n - 768)];
                }
                o[j] = (__bf16)v;
            }
            *(bf16x8*)(wt + (size_t)g * 8) = o;
        } else if (g < NWT) {
            int g2 = g - NW1;
            int c = g2 & 2047;
            int ct = g2 >> 11;
            int p = c >> 7, r = c & 127;
            int n = ct * 128 + r;
            int k0 = p * 8;
            bf16x8 o;
#pragma unroll
            for (int j = 0; j < 8; j++)
                o[j] = (__bf16)W2[(size_t)(k0 + j) * 512 + n];
            *(bf16x8*)(w2t + (size_t)g2 * 8) = o;
        } else if (g < NWT + 2048) {
            int g3 = g - NWT;
            int p = g3 >> 7, r = g3 & 127;
            bf16x8 o;
#pragma unroll
            for (int j = 0; j < 8; j++)
                o[j] = (__bf16)Wg1[(size_t)(p * 8 + j) * 128 + r];
            *(bf16x8*)(wgcn1s + (size_t)g3 * 8) = o;
        } else if (g < NWT2) {
            int g4 = g - NWT - 2048;
            int p = g4 >> 6, r = g4 & 63;
            bf16x8 o;
#pragma unroll
            for (int j = 0; j < 8; j++)
                o[j] = (__bf16)Wg2[(size_t)(p * 8 + j) * 64 + r];
            *(bf16x8*)(wgcn2s + (size_t)g4 * 8) = o;
        }
    } else {
        int e = (bid - NBX - WBLK) * 256 + tid;
        if (e < ET) {
            int s, d; edge_sd(ei, e, s, d);
            atomicAdd(&deg[d], 1);
        }
    }
}

// ---------------------------------------------------------------------------
// MFMA GEMM 1: xb @ wt^T -> h1b bf16[NN,768], skippre f32[NN,64], + fused
// alpha1. 128M x 128N block, 8 waves (32x64 each, 4x2), BK=64. 512 threads.
// (round-11 verified: ~57 us, MfmaUtil 26%, VGPR 40 — structural plateau;
//  5 alternative schedules tried r0-r8, all worse or neutral. FROZEN.)
// ---------------------------------------------------------------------------
__global__ __launch_bounds__(512)
void mfma_gemm1_kernel(const __bf16* __restrict__ xb, const __bf16* __restrict__ wt,
                       const float* __restrict__ a_src1, const float* __restrict__ a_dst1,
                       __bf16* __restrict__ h1b, float* __restrict__ skippre,
                       float* __restrict__ asrc, float* __restrict__ adst) {
    __shared__ __bf16 As[8192];    // 8 planes x 128 rows x 8 (16 KB)
    __shared__ __bf16 Bs[8192];    // 8 planes x 128 rows x 8 (16 KB)
    __shared__ float sA[128], sD[128];
    __shared__ float asd[256];
    int b = blockIdx.x;
    int xcd = b & 7, j = b >> 3;
    int jq = j / 7;
    int rt = xcd + 8 * jq;            // same-rt blocks share an XCD (A-slab L2 reuse)
    int ct = j - 7 * jq;
    if (rt >= MPAD / 128) return;     // 79 row tiles
    const int bi = rt * 128;
    const int bn = ct * 128;

    const int tid = threadIdx.x;
    const int lane = tid & 63;
    const int w = tid >> 6;           // 0..7
    const int wm = w >> 1;            // 0..3 : 32-row band
    const int wn = w & 1;             // 0..1 : 64-col half
    const int q = lane >> 4, m16 = lane & 15;

    if (tid < 128) { sA[tid] = 0.f; sD[tid] = 0.f; }
    if (ct < 6) {
        if (tid < 128)      asd[tid] = a_src1[ct * 128 + tid];
        else if (tid < 256) asd[tid] = a_dst1[ct * 128 + (tid - 128)];
    }

    f32x4 acc[2][4] = {};

    for (int ks = 0; ks < KPAD / 64; ks++) {
        // A: two adjacent 64-row slabs (rt*2, rt*2+1); 16 segs = p*2 + h
        const size_t slabA = ((size_t)(rt * 2) * 32 + ks) * 512;
        const size_t slabB = ((size_t)ct * 32 + ks) * 1024;
#pragma unroll
        for (int i = 0; i < 2; i++) {
            int seg = i * 8 + w;              // 0..15
            int p = seg >> 1, h = seg & 1;
            GLL(xb + (slabA + (size_t)h * 16384 + p * 64 + lane) * 8,
                As + seg * 512);              // As[(p*128 + h*64 + r)*8]
        }
#pragma unroll
        for (int i = 0; i < 2; i++) {
            int seg = i * 8 + w;              // 0..15 = p*2 + half
            GLL(wt + (slabB + seg * 64 + lane) * 8, Bs + seg * 512);
        }
        __syncthreads();

#pragma unroll
        for (int kk = 0; kk < 2; kk++) {
            const int pb = kk * 4 + q;
            bf16x8 af[2], bfr[4];
#pragma unroll
            for (int mt = 0; mt < 2; mt++)
                af[mt] = *(const bf16x8*)(As + (pb * 128 + wm * 32 + mt * 16 + m16) * 8);
#pragma unroll
            for (int nt = 0; nt < 4; nt++)
                bfr[nt] = *(const bf16x8*)(Bs + (pb * 128 + wn * 64 + nt * 16 + m16) * 8);
#pragma unroll
            for (int mt = 0; mt < 2; mt++)
#pragma unroll
                for (int nt = 0; nt < 4; nt++)
                    acc[mt][nt] = __builtin_amdgcn_mfma_f32_16x16x32_bf16(af[mt], bfr[nt], acc[mt][nt], 0, 0, 0);
        }
        __syncthreads();
    }

#pragma unroll
    for (int mt = 0; mt < 2; mt++) {
#pragma unroll
        for (int r = 0; r < 4; r++) {
            int rowl = wm * 32 + mt * 16 + q * 4 + r;
            int row = bi + rowl;
            float ps = 0.f, pd = 0.f;
#pragma unroll
            for (int nt = 0; nt < 4; nt++) {
                int coll = wn * 64 + nt * 16 + m16;
                int col = bn + coll;
                float v = acc[mt][nt][r];
                if (ct < 6) { ps += v * asd[coll]; pd += v * asd[128 + coll]; }
                if (row < NN) {
                    if (col < 768)      h1b[(size_t)row * 768 + col] = (__bf16)v;
                    else if (col < 832) skippre[(size_t)row * 64 + (col - 768)] = v;
                }
            }
            if (ct < 6) {
#pragma unroll
                for (int off = 1; off < 16; off <<= 1) {
                    ps += __shfl_xor(ps, off);
                    pd += __shfl_xor(pd, off);
                }
                if (m16 == 0) { atomicAdd(&sA[rowl], ps); atomicAdd(&sD[rowl], pd); }
            }
        }
    }
    if (ct < 6) {
        __syncthreads();
        if (tid < 128) {
            int row = bi + tid;
            if (row < NN) { asrc[row * 6 + ct] = sA[tid]; adst[row * 6 + ct] = sD[tid]; }
        }
    }
}

// ---------------------------------------------------------------------------
// MFMA GEMM 2: x1gcnb(swizzled)[MPAD,128] @ w2t(swizzled)[512,128]^T -> h2b
// bf16[NN,512], + fused alpha2. Round-18: retiled to gemm1's verified shape —
// 128M x 128N block, 8 waves (32x64, 4x2), K=128 (2 BK=64 steps), 512 thr.
// Halves staging + barriers per output vs the old 64x128/4-wave (m92/m103
// tile ladder + our r2 measurement). Grid dim3(4, 79) = 316 blocks.
// ---------------------------------------------------------------------------
__global__ __launch_bounds__(512)
void mfma_gemm2_kernel(const __bf16* __restrict__ A, const __bf16* __restrict__ B,
                       const float* __restrict__ a_src2, const float* __restrict__ a_dst2,
                       __bf16* __restrict__ h2b,
                       float* __restrict__ asrc, float* __restrict__ adst) {
    __shared__ __bf16 As[8192];    // 8 planes x 128 rows x 8 (16 KB)
    __shared__ __bf16 Bs[8192];
    __shared__ float sA[128], sD[128];
    __shared__ float asd[256];
    const int rt = blockIdx.y, ct = blockIdx.x;
    const int bi = rt * 128, bn = ct * 128;
    const int tid = threadIdx.x, lane = tid & 63, w = tid >> 6;
    const int wm = w >> 1, wn = w & 1;
    const int q = lane >> 4, m16 = lane & 15;

    if (tid < 128) { sA[tid] = 0.f; sD[tid] = 0.f; }
    if (tid < 128)      asd[tid] = a_src2[ct * 128 + tid];
    else if (tid < 256) asd[tid] = a_dst2[ct * 128 + (tid - 128)];

    f32x4 acc[2][4] = {};

    for (int ks = 0; ks < 2; ks++) {
        // A: two adjacent 64-row slabs (rt*2+h); plane p of this ks = ks*8+p
        const size_t slabB = (size_t)ct * 2048 + ks * 1024;
#pragma unroll
        for (int i = 0; i < 2; i++) {
            int seg = i * 8 + w;              // 0..15
            int p = seg >> 1, h = seg & 1;
            GLL(A + ((size_t)(rt * 2 + h) * 1024 + ks * 512 + p * 64 + lane) * 8,
                As + seg * 512);              // As[(p*128 + h*64 + r)*8]
        }
#pragma unroll
        for (int i = 0; i < 2; i++) {
            int seg = i * 8 + w;              // 0..15 = p*2 + half
            GLL(B + (slabB + seg * 64 + lane) * 8, Bs + seg * 512);
        }
        __syncthreads();

#pragma unroll
        for (int kk = 0; kk < 2; kk++) {
            const int pb = kk * 4 + q;
            bf16x8 af[2], bfr[4];
#pragma unroll
            for (int mt = 0; mt < 2; mt++)
                af[mt] = *(const bf16x8*)(As + (pb * 128 + wm * 32 + mt * 16 + m16) * 8);
#pragma unroll
            for (int nt = 0; nt < 4; nt++)
                bfr[nt] = *(const bf16x8*)(Bs + (pb * 128 + wn * 64 + nt * 16 + m16) * 8);
#pragma unroll
            for (int mt = 0; mt < 2; mt++)
#pragma unroll
                for (int nt = 0; nt < 4; nt++)
                    acc[mt][nt] = __builtin_amdgcn_mfma_f32_16x16x32_bf16(af[mt], bfr[nt], acc[mt][nt], 0, 0, 0);
        }
        __syncthreads();
    }

#pragma unroll
    for (int mt = 0; mt < 2; mt++) {
#pragma unroll
        for (int r = 0; r < 4; r++) {
            int rowl = wm * 32 + mt * 16 + q * 4 + r;
            int row = bi + rowl;
            float ps = 0.f, pd = 0.f;
#pragma unroll
            for (int nt = 0; nt < 4; nt++) {
                int coll = wn * 64 + nt * 16 + m16;
                float v = acc[mt][nt][r];
                ps += v * asd[coll]; pd += v * asd[128 + coll];
                if (row < NN) h2b[(size_t)row * 512 + bn + coll] = (__bf16)v;
            }
#pragma unroll
            for (int off = 1; off < 16; off <<= 1) {
                ps += __shfl_xor(ps, off);
                pd += __shfl_xor(pd, off);
            }
            if (m16 == 0) { atomicAdd(&sA[rowl], ps); atomicAdd(&sD[rowl], pd); }
        }
    }
    __syncthreads();
    if (tid < 128) {
        int row = bi + tid;
        if (row < NN) { asrc[row * 4 + ct] = sA[tid]; adst[row * 4 + ct] = sD[tid]; }
    }
}

// ---------------------------------------------------------------------------
// MFMA GCN GEMM: A(swizzled)[MPAD,128] @ Bs(swizzled)[NT,128]^T -> y bf16[NN,NT]
// 64M x NT block, 4 waves, BK=64 (2 iters), 256 threads. NT in {64,128}.
// ---------------------------------------------------------------------------
template<int NT>
__global__ __launch_bounds__(256)
void mfma_gcn_kernel(const __bf16* __restrict__ A, const __bf16* __restrict__ B,
                     __bf16* __restrict__ Cb) {
    __shared__ __bf16 As[4096];
    __shared__ __bf16 Bs[NT * 64];      // 8 planes x NT rows x 8
    const int rt = blockIdx.x;
    const int bi = rt * 64;
    const int tid = threadIdx.x, lane = tid & 63, w = tid >> 6;
    const int q = lane >> 4, m16 = lane & 15;
    constexpr int MT = (NT == 128) ? 2 : 1;
    constexpr int MSPAN = (NT == 128) ? 32 : 16;
    const int wm = (NT == 128) ? (w >> 1) : w;
    const int wn = (NT == 128) ? (w & 1) : 0;

    f32x4 acc[MT][4] = {};

    for (int ks = 0; ks < 2; ks++) {
        const size_t slabA = (size_t)rt * 1024 + ks * 512;
        const size_t slabB = (size_t)ks * (NT * 8);
#pragma unroll
        for (int i = 0; i < 2; i++) {
            int seg = i * 4 + w;
            GLL(A + (slabA + seg * 64 + lane) * 8, As + seg * 512);
        }
#pragma unroll
        for (int i = 0; i < NT / 32; i++) {
            int seg = i * 4 + w;
            GLL(B + (slabB + (size_t)seg * 64 + lane) * 8, Bs + seg * 512);
        }
        __syncthreads();

#pragma unroll
        for (int kk = 0; kk < 2; kk++) {
            const int pb = kk * 4 + q;
            bf16x8 af[MT], bfr[4];
#pragma unroll
            for (int mt = 0; mt < MT; mt++)
                af[mt] = *(const bf16x8*)(As + (pb * 64 + wm * MSPAN + mt * 16 + m16) * 8);
#pragma unroll
            for (int nt = 0; nt < 4; nt++)
                bfr[nt] = *(const bf16x8*)(Bs + (pb * NT + wn * 64 + nt * 16 + m16) * 8);
#pragma unroll
            for (int mt = 0; mt < MT; mt++)
#pragma unroll
                for (int nt = 0; nt < 4; nt++)
                    acc[mt][nt] = __builtin_amdgcn_mfma_f32_16x16x32_bf16(af[mt], bfr[nt], acc[mt][nt], 0, 0, 0);
        }
        __syncthreads();
    }

#pragma unroll
    for (int mt = 0; mt < MT; mt++) {
#pragma unroll
        for (int r = 0; r < 4; r++) {
            int row = bi + wm * MSPAN + mt * 16 + q * 4 + r;
            if (row >= NN) continue;
#pragma unroll
            for (int nt = 0; nt < 4; nt++) {
                int col = wn * 64 + nt * 16 + m16;
                Cb[(size_t)row * NT + col] = (__bf16)acc[mt][nt][r];
            }
        }
    }
}

// ---------------------------------------------------------------------------
// Fused segment-softmax + aggregation + head-mean + bias + LN + ReLU.
// T14 async prefetch, 4 edges/wave deep (r8-verified numerically).
// ---------------------------------------------------------------------------
template<int H>
__global__ void gat_agg_kernel(const __bf16* __restrict__ hb,
                               const float* __restrict__ asrc,
                               const float* __restrict__ adst,
                               const int* __restrict__ rowstart,
                               const int* __restrict__ csr_src,
                               const float* __restrict__ bias,
                               const float* __restrict__ gamma,
                               const float* __restrict__ beta,
                               __bf16* __restrict__ outs) {
    constexpr int CH = H * 128;
    constexpr int CAP = 128;
    int n = blockIdx.x;
    int t = threadIdx.x;
    int w = t >> 6, l = t & 63;
    __shared__ float invden[H];
    __shared__ float denp[256];
    __shared__ int   srcs[CAP];
    __shared__ float evs[CAP * H];
    __shared__ float sm[4 * CH];
    __shared__ float red[8];

    int s0 = rowstart[n];
    int deg = rowstart[n + 1] - s0;
    int degc = deg < CAP ? deg : CAP;
    float adst_n = (l < H) ? adst[n * H + l] : 0.f;   // for fallback path

    // phase 0: cooperative srcs load
    if (t < degc) srcs[t] = csr_src[s0 + t];
    __syncthreads();

    // prologue (T14): issue this wave's first FOUR h-row gathers now — they
    // depend only on srcs, so their latency overlaps all of phase 1.
    const int h0 = l >> 4;
    const int h1i = 4 + (l >> 5);
    const int i0 = w, i1 = w + 4, i2 = w + 8, i3 = w + 12;
    const bool has0 = i0 < degc, has1 = i1 < degc;
    const bool has2 = i2 < degc, has3 = i3 < degc;
    bf16x8 pg0, pg1, pg2, pg3; bf16x4 pe0, pe1, pe2, pe3;
    if (has0) {
        const __bf16* hp = hb + (size_t)srcs[i0] * CH;
        pg0 = *(const bf16x8*)(hp + l * 8);
        if (H == 6) pe0 = *(const bf16x4*)(hp + 512 + l * 4);
    }
    if (has1) {
        const __bf16* hp = hb + (size_t)srcs[i1] * CH;
        pg1 = *(const bf16x8*)(hp + l * 8);
        if (H == 6) pe1 = *(const bf16x4*)(hp + 512 + l * 4);
    }
    if (has2) {
        const __bf16* hp = hb + (size_t)srcs[i2] * CH;
        pg2 = *(const bf16x8*)(hp + l * 8);
        if (H == 6) pe2 = *(const bf16x4*)(hp + 512 + l * 4);
    }
    if (has3) {
        const __bf16* hp = hb + (size_t)srcs[i3] * CH;
        pg3 = *(const bf16x8*)(hp + l * 8);
        if (H == 6) pe3 = *(const bf16x4*)(hp + 512 + l * 4);
    }

    // phase 1: parallel over (edge, head): 8 lanes per edge, 32 edges/pass
    const int eh = t >> 3;      // edge slot within pass (0..31)
    const int hh1 = t & 7;      // head (hh1 < H active)
    float adst_h = (hh1 < H) ? adst[n * H + hh1] : 0.f;
    float dloc = 0.f;
    for (int base = 0; base < deg; base += 32) {
        int idx = base + eh;
        if (idx < deg && hh1 < H) {
            int src = (idx < CAP) ? srcs[idx] : csr_src[s0 + idx];
            float al = asrc[src * H + hh1] + adst_h;
            al = al >= 0.f ? al : 0.2f * al;
            float ev = __expf(al);
            dloc += ev;
            if (idx < CAP) evs[idx * H + hh1] = ev;
        }
    }
    denp[t] = dloc;
    __syncthreads();
    if (t < H) {
        float s = 0.f;
#pragma unroll
        for (int g = 0; g < 32; g++) s += denp[g * 8 + t];
        invden[t] = 1.f / s;
    }
    __syncthreads();

    // phase 2: weighted feature accumulation
    constexpr int NA = (H == 6) ? 12 : 8;
    float acc[NA] = {};
    // consume the preloaded edges (weights now available in evs)
    if (has0) {
        float w0 = evs[i0 * H + h0];
#pragma unroll
        for (int jj = 0; jj < 8; jj++) acc[jj] += (float)pg0[jj] * w0;
        if (H == 6) {
            float w1 = evs[i0 * H + h1i];
#pragma unroll
            for (int jj = 0; jj < 4; jj++) acc[8 + jj] += (float)pe0[jj] * w1;
        }
    }
    if (has1) {
        float w0 = evs[i1 * H + h0];
#pragma unroll
        for (int jj = 0; jj < 8; jj++) acc[jj] += (float)pg1[jj] * w0;
        if (H == 6) {
            float w1 = evs[i1 * H + h1i];
#pragma unroll
            for (int jj = 0; jj < 4; jj++) acc[8 + jj] += (float)pe1[jj] * w1;
        }
    }
    if (has2) {
        float w0 = evs[i2 * H + h0];
#pragma unroll
        for (int jj = 0; jj < 8; jj++) acc[jj] += (float)pg2[jj] * w0;
        if (H == 6) {
            float w1 = evs[i2 * H + h1i];
#pragma unroll
            for (int jj = 0; jj < 4; jj++) acc[8 + jj] += (float)pe2[jj] * w1;
        }
    }
    if (has3) {
        float w0 = evs[i3 * H + h0];
#pragma unroll
        for (int jj = 0; jj < 8; jj++) acc[jj] += (float)pg3[jj] * w0;
        if (H == 6) {
            float w1 = evs[i3 * H + h1i];
#pragma unroll
            for (int jj = 0; jj < 4; jj++) acc[8 + jj] += (float)pe3[jj] * w1;
        }
    }
    // remaining edges from w+16, 2-edge pipelined
    int idx = w + 16;
    for (; idx + 4 < degc; idx += 8) {
        int src0 = srcs[idx], src1 = srcs[idx + 4];
        float w00 = evs[idx * H + h0];
        float w10 = evs[(idx + 4) * H + h0];
        const __bf16* hp0 = hb + (size_t)src0 * CH;
        const __bf16* hp1 = hb + (size_t)src1 * CH;
        bf16x8 g00 = *(const bf16x8*)(hp0 + l * 8);
        bf16x8 g10 = *(const bf16x8*)(hp1 + l * 8);
#pragma unroll
        for (int jj = 0; jj < 8; jj++)
            acc[jj] += (float)g00[jj] * w00 + (float)g10[jj] * w10;
        if (H == 6) {
            float w01 = evs[idx * H + h1i];
            float w11 = evs[(idx + 4) * H + h1i];
            bf16x4 g01 = *(const bf16x4*)(hp0 + 512 + l * 4);
            bf16x4 g11 = *(const bf16x4*)(hp1 + 512 + l * 4);
#pragma unroll
            for (int jj = 0; jj < 4; jj++)
                acc[8 + jj] += (float)g01[jj] * w01 + (float)g11[jj] * w11;
        }
    }
    if (idx < degc) {
        int src = srcs[idx];
        float w0 = evs[idx * H + h0];
        const __bf16* hp = hb + (size_t)src * CH;
        bf16x8 hv = *(const bf16x8*)(hp + l * 8);
#pragma unroll
        for (int jj = 0; jj < 8; jj++) acc[jj] += (float)hv[jj] * w0;
        if (H == 6) {
            float w1 = evs[idx * H + h1i];
            bf16x4 hv1 = *(const bf16x4*)(hp + 512 + l * 4);
#pragma unroll
            for (int jj = 0; jj < 4; jj++) acc[8 + jj] += (float)hv1[jj] * w1;
        }
    }
    // fallback: uncached edges (deg > CAP; effectively never for this graph)
    for (int i2f = CAP + w; i2f < deg; i2f += 4) {
        int src = csr_src[s0 + i2f];
        float ev = 0.f;
        if (l < H) {
            float al = asrc[src * H + l] + adst_n;
            al = al >= 0.f ? al : 0.2f * al;
            ev = __expf(al);
        }
        const __bf16* hp = hb + (size_t)src * CH;
        float wgt = __shfl(ev, h0);
        bf16x8 hv = *(const bf16x8*)(hp + l * 8);
#pragma unroll
        for (int jj = 0; jj < 8; jj++) acc[jj] += (float)hv[jj] * wgt;
        if (H == 6) {
            float wg1 = __shfl(ev, h1i);
            bf16x4 hv1 = *(const bf16x4*)(hp + 512 + l * 4);
#pragma unroll
            for (int jj = 0; jj < 4; jj++) acc[8 + jj] += (float)hv1[jj] * wg1;
        }
    }

    *(f32x4*)(sm + w * CH + l * 8)     = *(f32x4*)(acc);
    *(f32x4*)(sm + w * CH + l * 8 + 4) = *(f32x4*)(acc + 4);
    if (H == 6)
        *(f32x4*)(sm + w * CH + 512 + l * 4) = *(f32x4*)(acc + 8);
    __syncthreads();

    float v = 0.f;
    if (t < 128) {
#pragma unroll
        for (int hh = 0; hh < H; hh++) {
            float hsum = 0.f;
#pragma unroll
            for (int ww = 0; ww < 4; ww++) hsum += sm[ww * CH + hh * 128 + t];
            v += hsum * invden[hh];
        }
        v = v * (1.f / H) + bias[t];
    }
    float sv = (t < 128) ? v : 0.f;
    float sq = (t < 128) ? v * v : 0.f;
#pragma unroll
    for (int off = 32; off; off >>= 1) {
        sv += __shfl_down(sv, off);
        sq += __shfl_down(sq, off);
    }
    if ((t & 63) == 0) { red[w * 2] = sv; red[w * 2 + 1] = sq; }
    __syncthreads();
    float tot = red[0] + red[2] + red[4] + red[6];
    float tsq = red[1] + red[3] + red[5] + red[7];
    float mu = tot * (1.f / 128.f);
    float var = tsq * (1.f / 128.f) - mu * mu;
    float r = rsqrtf(var + 1e-5f);
    if (t < 128) {
        float o = fmaxf((v - mu) * r * gamma[t] + beta[t], 0.f);
        // MFMA-A swizzled store: n -> (rt,r), t -> (p,off)
        int rt2 = n >> 6, rr = n & 63, pp = t >> 3, off2 = t & 7;
        outs[((size_t)(rt2 * 16 + pp) * 64 + rr) * 8 + off2] = (__bf16)o;
    }
}

// ---------------------------------------------------------------------------
// per-node GCN aggregation (round-15 vectorized): LPE lanes own 8 cols each
// (16B loads), G edge-groups in flight; LDS tree-reduce across groups.
// ---------------------------------------------------------------------------
template<int C>
__global__ void gcn_agg_kernel(const __bf16* __restrict__ y,
                               const float* __restrict__ dinv,
                               const int* __restrict__ rowstart,
                               const int* __restrict__ csr_src,
                               const float* __restrict__ bias,
                               float* __restrict__ out, int coloff,
                               __bf16* __restrict__ bout) {
    constexpr int LPE = C / 8;        // lanes per edge (16 or 8)
    constexpr int G = 128 / LPE;      // edge groups in flight (8 or 16)
    __shared__ float sm[G * C];       // 4 KB
    int n = blockIdx.x;
    int t = threadIdx.x;
    int lane = t & (LPE - 1);
    int grp = t / LPE;
    float acc[8] = {};
    int s0 = rowstart[n], s1 = rowstart[n + 1];
    for (int e = s0 + grp; e < s1; e += G) {
        int src = csr_src[e];
        float dv = dinv[src];
        bf16x8 v = *(const bf16x8*)(y + (size_t)src * C + lane * 8);
#pragma unroll
        for (int j = 0; j < 8; j++) acc[j] += (float)v[j] * dv;
    }
    *(f32x4*)(sm + grp * C + lane * 8)     = *(f32x4*)(acc);
    *(f32x4*)(sm + grp * C + lane * 8 + 4) = *(f32x4*)(acc + 4);
    __syncthreads();
    if (t < C) {
        float v = 0.f;
#pragma unroll
        for (int g = 0; g < G; g++) v += sm[g * C + t];
        v = fmaxf(v * dinv[n] + bias[t], 0.f);
        out[(size_t)n * 192 + coloff + t] = v;
        if (bout) {
            int rt = n >> 6, r = n & 63, p = t >> 3, off = t & 7;
            bout[((size_t)(rt * 16 + p) * 64 + r) * 8 + off] = (__bf16)v;
        }
    }
}

// ---------------------------------------------------------------------------
// Fused: fused=relu(cat@W_fuse+b_fuse); v=fused+relu(skippre+b_skip);
// LN(v) -> 64->32->16->5 MLP. (round-15: 16 nodes/block, verified)
// ---------------------------------------------------------------------------
__global__ __launch_bounds__(256)
void fuse_final_kernel(const float* __restrict__ cat,
                       const float* __restrict__ skippre,
                       const float* __restrict__ Wf, const float* __restrict__ bfz,
                       const float* __restrict__ b_skip,
                       const float* __restrict__ g3, const float* __restrict__ be3,
                       const float* __restrict__ Wc1, const float* __restrict__ bc1,
                       const float* __restrict__ Wc2, const float* __restrict__ bc2,
                       const float* __restrict__ Wc3, const float* __restrict__ bc3,
                       float* __restrict__ out) {
    __shared__ float WfS[192 * 64];     // 48 KB
    __shared__ float catS[4][4][196];   // 12.25 KB
    __shared__ float fS[4][64], h1S[4][32], h2S[4][16];
    int tid = threadIdx.x;
    int w = tid >> 6, l = tid & 63;
#pragma unroll
    for (int i = 0; i < 12; i++) {
        int idx = (i * 256 + tid) * 4;
        *(f32x4*)(WfS + idx) = *(const f32x4*)(Wf + idx);
    }
    int n0 = blockIdx.x * 16 + w * 4;
    float sk[4];
#pragma unroll
    for (int i = 0; i < 4; i++) {
        int n = n0 + i;
        if (n < NN) {
            catS[w][i][l]       = cat[(size_t)n * 192 + l];
            catS[w][i][64 + l]  = cat[(size_t)n * 192 + 64 + l];
            catS[w][i][128 + l] = cat[(size_t)n * 192 + 128 + l];
            sk[i] = fmaxf(skippre[(size_t)n * 64 + l] + b_skip[l], 0.f);
        } else {
            sk[i] = 0.f;
        }
    }
    __syncthreads();

#pragma unroll
    for (int i = 0; i < 4; i++) {
        int n = n0 + i;
        if (n < NN) {
            float fu = bfz[l];
#pragma unroll 4
            for (int k = 0; k < 192; k++)
                fu += catS[w][i][k] * WfS[k * 64 + l];
            float v = fmaxf(fu, 0.f) + sk[i];

            float sv = v, sq = v * v;
#pragma unroll
            for (int off = 32; off; off >>= 1) {
                sv += __shfl_xor(sv, off);
                sq += __shfl_xor(sq, off);
            }
            float mu = sv * (1.f / 64.f);
            float var = sq * (1.f / 64.f) - mu * mu;
            float r = rsqrtf(var + 1e-5f);
            fS[w][l] = (v - mu) * r * g3[l] + be3[l];
            // per-wave private LDS: no __syncthreads needed between stages
            if (l < 32) {
                float a = bc1[l];
                for (int k = 0; k < 64; k++) a += fS[w][k] * Wc1[k * 32 + l];
                h1S[w][l] = fmaxf(a, 0.f);
            }
            if (l < 16) {
                float a = bc2[l];
                for (int k = 0; k < 32; k++) a += h1S[w][k] * Wc2[k * 16 + l];
                h2S[w][l] = fmaxf(a, 0.f);
            }
            if (l < 5) {
                float a = bc3[l];
                for (int k = 0; k < 16; k++) a += h2S[w][k] * Wc3[k * 5 + l];
                out[(size_t)n * 5 + l] = a;
            }
        }
    }
}

// ---------------------------------------------------------------------------
extern "C" void kernel_launch(void* const* d_in, const int* in_sizes, int n_in,
                              void* d_out, int out_size, void* d_ws, size_t ws_size,
                              hipStream_t stream) {
    const float* x      = (const float*)d_in[0];
    const int*   ei     = (const int*)d_in[1];
    const float* W_gat1 = (const float*)d_in[2];
    const float* a_src1 = (const float*)d_in[3];
    const float* a_dst1 = (const float*)d_in[4];
    const float* b_gat1 = (const float*)d_in[5];
    const float* W_gcn1 = (const float*)d_in[6];
    const float* b_gcn1 = (const float*)d_in[7];
    const float* W_gat2 = (const float*)d_in[8];
    const float* a_src2 = (const float*)d_in[9];
    const float* a_dst2 = (const float*)d_in[10];
    const float* b_gat2 = (const float*)d_in[11];
    const float* W_gcn2 = (const float*)d_in[12];
    const float* b_gcn2 = (const float*)d_in[13];
    const float* W_skip = (const float*)d_in[14];
    const float* b_skip = (const float*)d_in[15];
    const float* W_fuse = (const float*)d_in[16];
    const float* b_fuse = (const float*)d_in[17];
    const float* W_c1   = (const float*)d_in[18];
    const float* b_c1   = (const float*)d_in[19];
    const float* W_c2   = (const float*)d_in[20];
    const float* b_c2   = (const float*)d_in[21];
    const float* W_c3   = (const float*)d_in[22];
    const float* b_c3   = (const float*)d_in[23];
    const float* g1     = (const float*)d_in[24];
    const float* be1    = (const float*)d_in[25];
    const float* g2     = (const float*)d_in[26];
    const float* be2    = (const float*)d_in[27];
    const float* g3     = (const float*)d_in[28];
    const float* be3    = (const float*)d_in[29];
    float* out = (float*)d_out;

    // workspace arena
    char* p = (char*)d_ws;
    auto alloc = [&](size_t bytes) {
        char* r = p; p += (bytes + 255) & ~(size_t)255; return r;
    };
    __bf16* xb      = (__bf16*)alloc((size_t)MPAD * KPAD * 2);   // 41.4 MB (swizzled)
    __bf16* wt      = (__bf16*)alloc((size_t)NPAD * KPAD * 2);   // 3.7 MB  (swizzled)
    __bf16* w2t     = (__bf16*)alloc((size_t)512 * 128 * 2);     // swizzled
    __bf16* wgcn1s  = (__bf16*)alloc((size_t)128 * 128 * 2);     // swizzled
    __bf16* wgcn2s  = (__bf16*)alloc((size_t)64 * 128 * 2);      // swizzled
    __bf16* h1b     = (__bf16*)alloc((size_t)NN * 768 * 2);      // 15.4 MB
    __bf16* h2b     = (__bf16*)alloc((size_t)NN * 512 * 2);      // 10.2 MB
    __bf16* ybufb   = (__bf16*)alloc((size_t)NN * 128 * 2);      // y1 reused y2
    // three swizzled activation buffers, contiguous for a single memset
    __bf16* x1gatb  = (__bf16*)alloc((size_t)3 * MPAD * 128 * 2);
    __bf16* x1gcnb  = x1gatb + (size_t)MPAD * 128;
    __bf16* x2gatb  = x1gcnb + (size_t)MPAD * 128;
    float* asrc     = (float*)alloc((size_t)NN * 6 * 4);
    float* adst     = (float*)alloc((size_t)NN * 6 * 4);
    int*   deg      = (int*)  alloc((size_t)2 * NN * 4);         // deg | cursor
    int*   cursor   = deg + NN;
    float* dinv     = (float*)alloc((size_t)NN * 4);
    int*   rowst    = (int*)  alloc((size_t)(NN + 1) * 4);
    int*   csrc     = (int*)  alloc((size_t)ET * 4);
    float* cat      = (float*)alloc((size_t)NN * 192 * 4);
    float* skippre  = (float*)alloc((size_t)NN * 64 * 4);

    hipMemsetAsync(deg, 0, (size_t)2 * NN * 4, stream);
    hipMemsetAsync(x1gatb, 0, (size_t)3 * MPAD * 128 * 2, stream);  // pad rows

    // merged conversions + degree count (round-12 verified)
    conv_kernel<<<NBX + WBLK + EB, 256, 0, stream>>>(
        x, xb, W_gat1, W_skip, W_gat2, W_gcn1, W_gcn2,
        wt, w2t, wgcn1s, wgcn2s, ei, deg);

    // CSR by dst
    scan_kernel   <<<1, 1024, 0, stream>>>(deg, rowst, dinv);
    scatter_kernel<<<EB, 256, 0, stream>>>(ei, rowst, cursor, csrc);

    // h1 (bf16) + skippre + fused alpha1, XCD-swizzled 128x128 BK=64, 8 waves
    // (round-11 verified structure, frozen)
    mfma_gemm1_kernel<<<560, 512, 0, stream>>>(xb, wt, a_src1, a_dst1,
                                               h1b, skippre, asrc, adst);

    // ---- GAT layer 1 (H=6) -> bf16 swizzled x1gatb ----
    gat_agg_kernel<6><<<NN, 256, 0, stream>>>(h1b, asrc, adst, rowst, csrc,
                                              b_gat1, g1, be1, x1gatb);
    // ---- GCN layer 1: y1 = x1gat @ W_gcn1 (MFMA) ----
    mfma_gcn_kernel<128><<<MPAD / 64, 256, 0, stream>>>(x1gatb, wgcn1s, ybufb);
    gcn_agg_kernel<128><<<NN, 128, 0, stream>>>(ybufb, dinv, rowst, csrc,
                                                b_gcn1, cat, 0, x1gcnb);
    // ---- GAT layer 2 (H=4): h2 + fused alpha2 (round-18: 8-wave 128x128) ----
    mfma_gemm2_kernel<<<dim3(4, MPAD / 128), 512, 0, stream>>>(
        x1gcnb, w2t, a_src2, a_dst2, h2b, asrc, adst);
    gat_agg_kernel<4><<<NN, 256, 0, stream>>>(h2b, asrc, adst, rowst, csrc,
                                              b_gat2, g2, be2, x2gatb);
    // ---- GCN layer 2: y2 = x2gat @ W_gcn2 (MFMA) -> cat[:, 128:192] ----
    mfma_gcn_kernel<64><<<MPAD / 64, 256, 0, stream>>>(x2gatb, wgcn2s, ybufb);
    gcn_agg_kernel<64><<<NN, 128, 0, stream>>>(ybufb, dinv, rowst, csrc,
                                               b_gcn2, cat, 128, nullptr);
    // ---- fuse + final (round-15: 16 nodes/block) ----
    fuse_final_kernel<<<(NN + 15) / 16, 256, 0, stream>>>(
        cat, skippre, W_fuse, b_fuse, b_skip, g3, be3,
        W_c1, b_c1, W_c2, b_c2, W_c3, b_c3, out);
}

// Round 10
// 399.441 us; speedup vs baseline: 1.0954x; 1.0149x over previous
//
#include <hip/hip_runtime.h>
#include <cstdint>
#include <cstddef>

#define NN 10000
#define NE 160000
#define ET (NE + NN)          // edges + self loops
#define FIN 2000
#define MPAD 10112            // 158 * 64
#define KPAD 2048
#define NPAD 896              // 7 * 128 (768 gat1 cols + 64 skip + 64 pad)

typedef __bf16 bf16x8 __attribute__((ext_vector_type(8)));
typedef __bf16 bf16x4 __attribute__((ext_vector_type(4)));
typedef float  f32x4  __attribute__((ext_vector_type(4)));

#define GLL(src, dst) __builtin_amdgcn_global_load_lds( \
    (const __attribute__((address_space(1))) void*)(src), \
    (__attribute__((address_space(3))) void*)(dst), 16, 0, 0)

// ---------------------------------------------------------------------------
// CSR build
// ---------------------------------------------------------------------------
__device__ __forceinline__ void edge_sd(const int* ei, int e, int& s, int& d) {
    if (e < NE) { s = ei[e]; d = ei[NE + e]; }
    else        { s = e - NE; d = e - NE; }
}

// exclusive scan over deg -> rowstart[0..NN]; also dinv = deg^-1/2
// (round-16: 1024 threads)
__global__ __launch_bounds__(1024)
void scan_kernel(const int* deg, int* rowstart, float* dinv) {
    __shared__ int wsum[16];
    const int T = 1024;
    int chunk = (NN + T - 1) / T;        // 10
    int t = threadIdx.x;
    int begin = t * chunk;
    int end = begin + chunk; if (end > NN) end = NN;
    if (begin > NN) begin = NN;
    int s = 0;
    for (int i = begin; i < end; i++) s += deg[i];
    int inc = s;
#pragma unroll
    for (int off = 1; off < 64; off <<= 1) {
        int u = __shfl_up(inc, off);
        if ((t & 63) >= off) inc += u;
    }
    if ((t & 63) == 63) wsum[t >> 6] = inc;
    __syncthreads();
    int woff = 0;
    for (int wv = 0; wv < (t >> 6); wv++) woff += wsum[wv];
    int run = woff + inc - s;            // exclusive prefix for this thread
    for (int i = begin; i < end; i++) {
        rowstart[i] = run; run += deg[i];
        int dg = deg[i];
        dinv[i] = dg > 0 ? rsqrtf((float)dg) : 0.f;
    }
    if (end == NN) rowstart[NN] = run;
}

__global__ void scatter_kernel(const int* ei, const int* rowstart, int* cursor,
                               int* csr_src) {
    int e = blockIdx.x * blockDim.x + threadIdx.x;
    if (e >= ET) return;
    int s, d; edge_sd(ei, e, s, d);
    int pos = atomicAdd(&cursor[d], 1);
    csr_src[rowstart[d] + pos] = s;
}

// ---------------------------------------------------------------------------
// Merged conversion + degree count (round-12 layout, round-19 load schedule).
// xb branch: ALL 16 f32x4 loads issued into named registers BEFORE any
// cvt/LDS-write (4x deeper per-thread load queue; was 2.7 TB/s with loads
// interleaved 4-at-a-time against pack VALU). Layout/swizzle unchanged.
// xb chunk c = ((rt*32 + ks)*8 + p)*64 + r holds x[rt*64+r][ks*64+p*8 ..+8)
// wt chunk: ((ct*32 + ks)*8 + p)*128 + r ; w2t chunk: (ct*16 + p)*128 + r
// wgcn1s chunk: p*128 + r (p 0..15) ; wgcn2s chunk: p*64 + r (p 0..15)
// ---------------------------------------------------------------------------
#define NBX (158 * 8)
#define NW1 (NPAD * KPAD / 8)                 // 229376
#define NWT (NW1 + 512 * 128 / 8)             // 237568
#define NWT2 (NWT + 2048 + 1024)              // + wgcn1s + wgcn2s
#define WBLK ((NWT2 + 255) / 256)
#define EB 665                                 // ceil(ET/256)
__global__ void conv_kernel(const float* __restrict__ x, __bf16* __restrict__ xb,
                            const float* __restrict__ Wg, const float* __restrict__ Ws,
                            const float* __restrict__ W2,
                            const float* __restrict__ Wg1, const float* __restrict__ Wg2,
                            __bf16* __restrict__ wt, __bf16* __restrict__ w2t,
                            __bf16* __restrict__ wgcn1s, __bf16* __restrict__ wgcn2s,
                            const int* __restrict__ ei, int* __restrict__ deg) {
    __shared__ __bf16 ls[16384];   // 32 KB: 4 slabs x 8 p x 64 r x 8 (swizzled)
    int bid = blockIdx.x;
    int tid = threadIdx.x;
    if (bid < NBX) {
        int rt = bid >> 3, kb = bid & 7;       // 64-row tile, 256-k tile
        const int lane16 = tid & 15;           // k-chunk owner within row
        const int ksl = lane16 >> 2;           // slab 0..3
        const int p0 = (lane16 & 3) * 2;       // p pair {p0, p0+1}
        const int rbase = tid >> 4;            // 0..15
        const int kg0 = kb * 256 + lane16 * 16;
        const int rsw_x = (p0 & 6) ^ ksl;      // swizzle const for this thread

        // phase A: issue all 16 loads (fully unrolled -> static reg indices)
        f32x4 f[16];
#pragma unroll
        for (int pass = 0; pass < 4; pass++) {
            int row = rt * 64 + pass * 16 + rbase;
            const float* xr = x + (size_t)row * FIN;
#pragma unroll
            for (int j = 0; j < 4; j++) {
                int k = kg0 + j * 4;
                if (row < NN && k + 3 < FIN)
                    f[pass * 4 + j] = *(const f32x4*)(xr + k);
                else
                    f[pass * 4 + j] = (f32x4){0.f, 0.f, 0.f, 0.f};
            }
        }
        // phase B: pack + swizzled LDS writes
#pragma unroll
        for (int pass = 0; pass < 4; pass++) {
            int r = pass * 16 + rbase;
            bf16x8 v0, v1;
#pragma unroll
            for (int j = 0; j < 4; j++) {
                f32x4 ff = f[pass * 4 + j];
                int o = (j & 1) * 4;
                if (j < 2) {
                    v0[o] = (__bf16)ff[0]; v0[o+1] = (__bf16)ff[1];
                    v0[o+2] = (__bf16)ff[2]; v0[o+3] = (__bf16)ff[3];
                } else {
                    v1[o] = (__bf16)ff[0]; v1[o+1] = (__bf16)ff[1];
                    v1[o+2] = (__bf16)ff[2]; v1[o+3] = (__bf16)ff[3];
                }
            }
            int rsw = r ^ rsw_x;
            *(bf16x8*)(ls + (((ksl * 8 + p0) * 64 + rsw) * 8))     = v0;
            *(bf16x8*)(ls + (((ksl * 8 + p0 + 1) * 64 + rsw) * 8)) = v1;
        }
        __syncthreads();
        size_t cbase = ((size_t)rt * 32 + kb * 4) * 512;
#pragma unroll
        for (int i = 0; i < 8; i++) {
            int g = i * 256 + tid;             // 0..2047
            int ksl2 = g >> 9, rem = g & 511;
            int p = rem >> 6, rr = rem & 63;
            int rsw = rr ^ ((p & 6) ^ ksl2);
            bf16x8 v = *(const bf16x8*)(ls + (((ksl2 * 8 + p) * 64 + rsw) * 8));
            *(bf16x8*)(xb + (cbase + (size_t)ksl2 * 512 + (p * 64 + rr)) * 8) = v;
        }
    } else if (bid < NBX + WBLK) {
        int g = (bid - NBX) * 256 + tid;
        if (g < NW1) {
            int r = g & 127, p = (g >> 7) & 7, ks = (g >> 10) & 31, ct = g >> 15;
            int n = ct * 128 + r;
            int k0 = ks * 64 + p * 8;
            bf16x8 o;
#pragma unroll
            for (int j = 0; j < 8; j++) {
                int k = k0 + j;
                float v = 0.f;
                if (k < FIN) {
                    if (n < 768)      v = Wg[(size_t)k * 768 + n];
                    else if (n < 832) v = Ws[(size_t)k * 64 + (n - 768)];
                }
                o[j] = (__bf16)v;
            }
            *(bf16x8*)(wt + (size_t)g * 8) = o;
        } else if (g < NWT) {
            int g2 = g - NW1;
            int c = g2 & 2047;
            int ct = g2 >> 11;
            int p = c >> 7, r = c & 127;
            int n = ct * 128 + r;
            int k0 = p * 8;
            bf16x8 o;
#pragma unroll
            for (int j = 0; j < 8; j++)
                o[j] = (__bf16)W2[(size_t)(k0 + j) * 512 + n];
            *(bf16x8*)(w2t + (size_t)g2 * 8) = o;
        } else if (g < NWT + 2048) {
            int g3 = g - NWT;
            int p = g3 >> 7, r = g3 & 127;
            bf16x8 o;
#pragma unroll
            for (int j = 0; j < 8; j++)
                o[j] = (__bf16)Wg1[(size_t)(p * 8 + j) * 128 + r];
            *(bf16x8*)(wgcn1s + (size_t)g3 * 8) = o;
        } else if (g < NWT2) {
            int g4 = g - NWT - 2048;
            int p = g4 >> 6, r = g4 & 63;
            bf16x8 o;
#pragma unroll
            for (int j = 0; j < 8; j++)
                o[j] = (__bf16)Wg2[(size_t)(p * 8 + j) * 64 + r];
            *(bf16x8*)(wgcn2s + (size_t)g4 * 8) = o;
        }
    } else {
        int e = (bid - NBX - WBLK) * 256 + tid;
        if (e < ET) {
            int s, d; edge_sd(ei, e, s, d);
            atomicAdd(&deg[d], 1);
        }
    }
}

// ---------------------------------------------------------------------------
// MFMA GEMM 1: xb @ wt^T -> h1b bf16[NN,768], skippre f32[NN,64], + fused
// alpha1. 128M x 128N block, 8 waves (32x64 each, 4x2), BK=64. 512 threads.
// (round-11 verified: ~57 us, MfmaUtil 26%, VGPR 40 — FROZEN.)
// ---------------------------------------------------------------------------
__global__ __launch_bounds__(512)
void mfma_gemm1_kernel(const __bf16* __restrict__ xb, const __bf16* __restrict__ wt,
                       const float* __restrict__ a_src1, const float* __restrict__ a_dst1,
                       __bf16* __restrict__ h1b, float* __restrict__ skippre,
                       float* __restrict__ asrc, float* __restrict__ adst) {
    __shared__ __bf16 As[8192];    // 8 planes x 128 rows x 8 (16 KB)
    __shared__ __bf16 Bs[8192];    // 8 planes x 128 rows x 8 (16 KB)
    __shared__ float sA[128], sD[128];
    __shared__ float asd[256];
    int b = blockIdx.x;
    int xcd = b & 7, j = b >> 3;
    int jq = j / 7;
    int rt = xcd + 8 * jq;            // same-rt blocks share an XCD (A-slab L2 reuse)
    int ct = j - 7 * jq;
    if (rt >= MPAD / 128) return;     // 79 row tiles
    const int bi = rt * 128;
    const int bn = ct * 128;

    const int tid = threadIdx.x;
    const int lane = tid & 63;
    const int w = tid >> 6;           // 0..7
    const int wm = w >> 1;            // 0..3 : 32-row band
    const int wn = w & 1;             // 0..1 : 64-col half
    const int q = lane >> 4, m16 = lane & 15;

    if (tid < 128) { sA[tid] = 0.f; sD[tid] = 0.f; }
    if (ct < 6) {
        if (tid < 128)      asd[tid] = a_src1[ct * 128 + tid];
        else if (tid < 256) asd[tid] = a_dst1[ct * 128 + (tid - 128)];
    }

    f32x4 acc[2][4] = {};

    for (int ks = 0; ks < KPAD / 64; ks++) {
        // A: two adjacent 64-row slabs (rt*2, rt*2+1); 16 segs = p*2 + h
        const size_t slabA = ((size_t)(rt * 2) * 32 + ks) * 512;
        const size_t slabB = ((size_t)ct * 32 + ks) * 1024;
#pragma unroll
        for (int i = 0; i < 2; i++) {
            int seg = i * 8 + w;              // 0..15
            int p = seg >> 1, h = seg & 1;
            GLL(xb + (slabA + (size_t)h * 16384 + p * 64 + lane) * 8,
                As + seg * 512);              // As[(p*128 + h*64 + r)*8]
        }
#pragma unroll
        for (int i = 0; i < 2; i++) {
            int seg = i * 8 + w;              // 0..15 = p*2 + half
            GLL(wt + (slabB + seg * 64 + lane) * 8, Bs + seg * 512);
        }
        __syncthreads();

#pragma unroll
        for (int kk = 0; kk < 2; kk++) {
            const int pb = kk * 4 + q;
            bf16x8 af[2], bfr[4];
#pragma unroll
            for (int mt = 0; mt < 2; mt++)
                af[mt] = *(const bf16x8*)(As + (pb * 128 + wm * 32 + mt * 16 + m16) * 8);
#pragma unroll
            for (int nt = 0; nt < 4; nt++)
                bfr[nt] = *(const bf16x8*)(Bs + (pb * 128 + wn * 64 + nt * 16 + m16) * 8);
#pragma unroll
            for (int mt = 0; mt < 2; mt++)
#pragma unroll
                for (int nt = 0; nt < 4; nt++)
                    acc[mt][nt] = __builtin_amdgcn_mfma_f32_16x16x32_bf16(af[mt], bfr[nt], acc[mt][nt], 0, 0, 0);
        }
        __syncthreads();
    }

#pragma unroll
    for (int mt = 0; mt < 2; mt++) {
#pragma unroll
        for (int r = 0; r < 4; r++) {
            int rowl = wm * 32 + mt * 16 + q * 4 + r;
            int row = bi + rowl;
            float ps = 0.f, pd = 0.f;
#pragma unroll
            for (int nt = 0; nt < 4; nt++) {
                int coll = wn * 64 + nt * 16 + m16;
                int col = bn + coll;
                float v = acc[mt][nt][r];
                if (ct < 6) { ps += v * asd[coll]; pd += v * asd[128 + coll]; }
                if (row < NN) {
                    if (col < 768)      h1b[(size_t)row * 768 + col] = (__bf16)v;
                    else if (col < 832) skippre[(size_t)row * 64 + (col - 768)] = v;
                }
            }
            if (ct < 6) {
#pragma unroll
                for (int off = 1; off < 16; off <<= 1) {
                    ps += __shfl_xor(ps, off);
                    pd += __shfl_xor(pd, off);
                }
                if (m16 == 0) { atomicAdd(&sA[rowl], ps); atomicAdd(&sD[rowl], pd); }
            }
        }
    }
    if (ct < 6) {
        __syncthreads();
        if (tid < 128) {
            int row = bi + tid;
            if (row < NN) { asrc[row * 6 + ct] = sA[tid]; adst[row * 6 + ct] = sD[tid]; }
        }
    }
}

// ---------------------------------------------------------------------------
// MFMA GEMM 2: x1gcnb(swizzled)[MPAD,128] @ w2t(swizzled)[512,128]^T -> h2b
// bf16[NN,512], + fused alpha2. 64x128 block, 4 waves (32x64), BK=64, 256 thr.
// (round-7 verified config; r18's 128x128 retile was neutral-negative —
//  316 blocks = 1.2/CU residency loss. Reverted.)
// ---------------------------------------------------------------------------
__global__ __launch_bounds__(256)
void mfma_gemm2_kernel(const __bf16* __restrict__ A, const __bf16* __restrict__ B,
                       const float* __restrict__ a_src2, const float* __restrict__ a_dst2,
                       __bf16* __restrict__ h2b,
                       float* __restrict__ asrc, float* __restrict__ adst) {
    __shared__ __bf16 As[4096];
    __shared__ __bf16 Bs[8192];
    __shared__ float sA[64], sD[64];
    __shared__ float asd[256];
    const int rt = blockIdx.y, ct = blockIdx.x;
    const int bi = rt * 64, bn = ct * 128;
    const int tid = threadIdx.x, lane = tid & 63, w = tid >> 6;
    const int wm = w >> 1, wn = w & 1;
    const int q = lane >> 4, m16 = lane & 15;

    if (tid < 64) { sA[tid] = 0.f; sD[tid] = 0.f; }
    if (tid < 128) asd[tid] = a_src2[ct * 128 + tid];
    else           asd[tid] = a_dst2[ct * 128 + (tid - 128)];

    f32x4 acc[2][4] = {};

    for (int ks = 0; ks < 2; ks++) {
        const size_t slabA = (size_t)rt * 1024 + ks * 512;
        const size_t slabB = (size_t)ct * 2048 + ks * 1024;
#pragma unroll
        for (int i = 0; i < 2; i++) {
            int seg = i * 4 + w;
            GLL(A + (slabA + seg * 64 + lane) * 8, As + seg * 512);
        }
#pragma unroll
        for (int i = 0; i < 4; i++) {
            int seg = i * 4 + w;
            GLL(B + (slabB + seg * 64 + lane) * 8, Bs + seg * 512);
        }
        __syncthreads();

#pragma unroll
        for (int kk = 0; kk < 2; kk++) {
            const int pb = kk * 4 + q;
            bf16x8 af[2], bfr[4];
#pragma unroll
            for (int mt = 0; mt < 2; mt++)
                af[mt] = *(const bf16x8*)(As + (pb * 64 + wm * 32 + mt * 16 + m16) * 8);
#pragma unroll
            for (int nt = 0; nt < 4; nt++)
                bfr[nt] = *(const bf16x8*)(Bs + (pb * 128 + wn * 64 + nt * 16 + m16) * 8);
#pragma unroll
            for (int mt = 0; mt < 2; mt++)
#pragma unroll
                for (int nt = 0; nt < 4; nt++)
                    acc[mt][nt] = __builtin_amdgcn_mfma_f32_16x16x32_bf16(af[mt], bfr[nt], acc[mt][nt], 0, 0, 0);
        }
        __syncthreads();
    }

#pragma unroll
    for (int mt = 0; mt < 2; mt++) {
#pragma unroll
        for (int r = 0; r < 4; r++) {
            int rowl = wm * 32 + mt * 16 + q * 4 + r;
            int row = bi + rowl;
            float ps = 0.f, pd = 0.f;
#pragma unroll
            for (int nt = 0; nt < 4; nt++) {
                int coll = wn * 64 + nt * 16 + m16;
                float v = acc[mt][nt][r];
                ps += v * asd[coll]; pd += v * asd[128 + coll];
                if (row < NN) h2b[(size_t)row * 512 + bn + coll] = (__bf16)v;
            }
#pragma unroll
            for (int off = 1; off < 16; off <<= 1) {
                ps += __shfl_xor(ps, off);
                pd += __shfl_xor(pd, off);
            }
            if (m16 == 0) { atomicAdd(&sA[rowl], ps); atomicAdd(&sD[rowl], pd); }
        }
    }
    __syncthreads();
    if (tid < 64) {
        int row = bi + tid;
        if (row < NN) { asrc[row * 4 + ct] = sA[tid]; adst[row * 4 + ct] = sD[tid]; }
    }
}

// ---------------------------------------------------------------------------
// MFMA GCN GEMM: A(swizzled)[MPAD,128] @ Bs(swizzled)[NT,128]^T -> y bf16[NN,NT]
// 64M x NT block, 4 waves, BK=64 (2 iters), 256 threads. NT in {64,128}.
// ---------------------------------------------------------------------------
template<int NT>
__global__ __launch_bounds__(256)
void mfma_gcn_kernel(const __bf16* __restrict__ A, const __bf16* __restrict__ B,
                     __bf16* __restrict__ Cb) {
    __shared__ __bf16 As[4096];
    __shared__ __bf16 Bs[NT * 64];      // 8 planes x NT rows x 8
    const int rt = blockIdx.x;
    const int bi = rt * 64;
    const int tid = threadIdx.x, lane = tid & 63, w = tid >> 6;
    const int q = lane >> 4, m16 = lane & 15;
    constexpr int MT = (NT == 128) ? 2 : 1;
    constexpr int MSPAN = (NT == 128) ? 32 : 16;
    const int wm = (NT == 128) ? (w >> 1) : w;
    const int wn = (NT == 128) ? (w & 1) : 0;

    f32x4 acc[MT][4] = {};

    for (int ks = 0; ks < 2; ks++) {
        const size_t slabA = (size_t)rt * 1024 + ks * 512;
        const size_t slabB = (size_t)ks * (NT * 8);
#pragma unroll
        for (int i = 0; i < 2; i++) {
            int seg = i * 4 + w;
            GLL(A + (slabA + seg * 64 + lane) * 8, As + seg * 512);
        }
#pragma unroll
        for (int i = 0; i < NT / 32; i++) {
            int seg = i * 4 + w;
            GLL(B + (slabB + (size_t)seg * 64 + lane) * 8, Bs + seg * 512);
        }
        __syncthreads();

#pragma unroll
        for (int kk = 0; kk < 2; kk++) {
            const int pb = kk * 4 + q;
            bf16x8 af[MT], bfr[4];
#pragma unroll
            for (int mt = 0; mt < MT; mt++)
                af[mt] = *(const bf16x8*)(As + (pb * 64 + wm * MSPAN + mt * 16 + m16) * 8);
#pragma unroll
            for (int nt = 0; nt < 4; nt++)
                bfr[nt] = *(const bf16x8*)(Bs + (pb * NT + wn * 64 + nt * 16 + m16) * 8);
#pragma unroll
            for (int mt = 0; mt < MT; mt++)
#pragma unroll
                for (int nt = 0; nt < 4; nt++)
                    acc[mt][nt] = __builtin_amdgcn_mfma_f32_16x16x32_bf16(af[mt], bfr[nt], acc[mt][nt], 0, 0, 0);
        }
        __syncthreads();
    }

#pragma unroll
    for (int mt = 0; mt < MT; mt++) {
#pragma unroll
        for (int r = 0; r < 4; r++) {
            int row = bi + wm * MSPAN + mt * 16 + q * 4 + r;
            if (row >= NN) continue;
#pragma unroll
            for (int nt = 0; nt < 4; nt++) {
                int col = wn * 64 + nt * 16 + m16;
                Cb[(size_t)row * NT + col] = (__bf16)acc[mt][nt][r];
            }
        }
    }
}

// ---------------------------------------------------------------------------
// Fused segment-softmax + aggregation + head-mean + bias + LN + ReLU.
// T14 async prefetch, 4 edges/wave deep (r8/r9-verified numerically).
// ---------------------------------------------------------------------------
template<int H>
__global__ void gat_agg_kernel(const __bf16* __restrict__ hb,
                               const float* __restrict__ asrc,
                               const float* __restrict__ adst,
                               const int* __restrict__ rowstart,
                               const int* __restrict__ csr_src,
                               const float* __restrict__ bias,
                               const float* __restrict__ gamma,
                               const float* __restrict__ beta,
                               __bf16* __restrict__ outs) {
    constexpr int CH = H * 128;
    constexpr int CAP = 128;
    int n = blockIdx.x;
    int t = threadIdx.x;
    int w = t >> 6, l = t & 63;
    __shared__ float invden[H];
    __shared__ float denp[256];
    __shared__ int   srcs[CAP];
    __shared__ float evs[CAP * H];
    __shared__ float sm[4 * CH];
    __shared__ float red[8];

    int s0 = rowstart[n];
    int deg = rowstart[n + 1] - s0;
    int degc = deg < CAP ? deg : CAP;
    float adst_n = (l < H) ? adst[n * H + l] : 0.f;   // for fallback path

    // phase 0: cooperative srcs load
    if (t < degc) srcs[t] = csr_src[s0 + t];
    __syncthreads();

    // prologue (T14): issue this wave's first FOUR h-row gathers now — they
    // depend only on srcs, so their latency overlaps all of phase 1.
    const int h0 = l >> 4;
    const int h1i = 4 + (l >> 5);
    const int i0 = w, i1 = w + 4, i2 = w + 8, i3 = w + 12;
    const bool has0 = i0 < degc, has1 = i1 < degc;
    const bool has2 = i2 < degc, has3 = i3 < degc;
    bf16x8 pg0, pg1, pg2, pg3; bf16x4 pe0, pe1, pe2, pe3;
    if (has0) {
        const __bf16* hp = hb + (size_t)srcs[i0] * CH;
        pg0 = *(const bf16x8*)(hp + l * 8);
        if (H == 6) pe0 = *(const bf16x4*)(hp + 512 + l * 4);
    }
    if (has1) {
        const __bf16* hp = hb + (size_t)srcs[i1] * CH;
        pg1 = *(const bf16x8*)(hp + l * 8);
        if (H == 6) pe1 = *(const bf16x4*)(hp + 512 + l * 4);
    }
    if (has2) {
        const __bf16* hp = hb + (size_t)srcs[i2] * CH;
        pg2 = *(const bf16x8*)(hp + l * 8);
        if (H == 6) pe2 = *(const bf16x4*)(hp + 512 + l * 4);
    }
    if (has3) {
        const __bf16* hp = hb + (size_t)srcs[i3] * CH;
        pg3 = *(const bf16x8*)(hp + l * 8);
        if (H == 6) pe3 = *(const bf16x4*)(hp + 512 + l * 4);
    }

    // phase 1: parallel over (edge, head): 8 lanes per edge, 32 edges/pass
    const int eh = t >> 3;      // edge slot within pass (0..31)
    const int hh1 = t & 7;      // head (hh1 < H active)
    float adst_h = (hh1 < H) ? adst[n * H + hh1] : 0.f;
    float dloc = 0.f;
    for (int base = 0; base < deg; base += 32) {
        int idx = base + eh;
        if (idx < deg && hh1 < H) {
            int src = (idx < CAP) ? srcs[idx] : csr_src[s0 + idx];
            float al = asrc[src * H + hh1] + adst_h;
            al = al >= 0.f ? al : 0.2f * al;
            float ev = __expf(al);
            dloc += ev;
            if (idx < CAP) evs[idx * H + hh1] = ev;
        }
    }
    denp[t] = dloc;
    __syncthreads();
    if (t < H) {
        float s = 0.f;
#pragma unroll
        for (int g = 0; g < 32; g++) s += denp[g * 8 + t];
        invden[t] = 1.f / s;
    }
    __syncthreads();

    // phase 2: weighted feature accumulation
    constexpr int NA = (H == 6) ? 12 : 8;
    float acc[NA] = {};
    // consume the preloaded edges (weights now available in evs)
    if (has0) {
        float w0 = evs[i0 * H + h0];
#pragma unroll
        for (int jj = 0; jj < 8; jj++) acc[jj] += (float)pg0[jj] * w0;
        if (H == 6) {
            float w1 = evs[i0 * H + h1i];
#pragma unroll
            for (int jj = 0; jj < 4; jj++) acc[8 + jj] += (float)pe0[jj] * w1;
        }
    }
    if (has1) {
        float w0 = evs[i1 * H + h0];
#pragma unroll
        for (int jj = 0; jj < 8; jj++) acc[jj] += (float)pg1[jj] * w0;
        if (H == 6) {
            float w1 = evs[i1 * H + h1i];
#pragma unroll
            for (int jj = 0; jj < 4; jj++) acc[8 + jj] += (float)pe1[jj] * w1;
        }
    }
    if (has2) {
        float w0 = evs[i2 * H + h0];
#pragma unroll
        for (int jj = 0; jj < 8; jj++) acc[jj] += (float)pg2[jj] * w0;
        if (H == 6) {
            float w1 = evs[i2 * H + h1i];
#pragma unroll
            for (int jj = 0; jj < 4; jj++) acc[8 + jj] += (float)pe2[jj] * w1;
        }
    }
    if (has3) {
        float w0 = evs[i3 * H + h0];
#pragma unroll
        for (int jj = 0; jj < 8; jj++) acc[jj] += (float)pg3[jj] * w0;
        if (H == 6) {
            float w1 = evs[i3 * H + h1i];
#pragma unroll
            for (int jj = 0; jj < 4; jj++) acc[8 + jj] += (float)pe3[jj] * w1;
        }
    }
    // remaining edges from w+16, 2-edge pipelined
    int idx = w + 16;
    for (; idx + 4 < degc; idx += 8) {
        int src0 = srcs[idx], src1 = srcs[idx + 4];
        float w00 = evs[idx * H + h0];
        float w10 = evs[(idx + 4) * H + h0];
        const __bf16* hp0 = hb + (size_t)src0 * CH;
        const __bf16* hp1 = hb + (size_t)src1 * CH;
        bf16x8 g00 = *(const bf16x8*)(hp0 + l * 8);
        bf16x8 g10 = *(const bf16x8*)(hp1 + l * 8);
#pragma unroll
        for (int jj = 0; jj < 8; jj++)
            acc[jj] += (float)g00[jj] * w00 + (float)g10[jj] * w10;
        if (H == 6) {
            float w01 = evs[idx * H + h1i];
            float w11 = evs[(idx + 4) * H + h1i];
            bf16x4 g01 = *(const bf16x4*)(hp0 + 512 + l * 4);
            bf16x4 g11 = *(const bf16x4*)(hp1 + 512 + l * 4);
#pragma unroll
            for (int jj = 0; jj < 4; jj++)
                acc[8 + jj] += (float)g01[jj] * w01 + (float)g11[jj] * w11;
        }
    }
    if (idx < degc) {
        int src = srcs[idx];
        float w0 = evs[idx * H + h0];
        const __bf16* hp = hb + (size_t)src * CH;
        bf16x8 hv = *(const bf16x8*)(hp + l * 8);
#pragma unroll
        for (int jj = 0; jj < 8; jj++) acc[jj] += (float)hv[jj] * w0;
        if (H == 6) {
            float w1 = evs[idx * H + h1i];
            bf16x4 hv1 = *(const bf16x4*)(hp + 512 + l * 4);
#pragma unroll
            for (int jj = 0; jj < 4; jj++) acc[8 + jj] += (float)hv1[jj] * w1;
        }
    }
    // fallback: uncached edges (deg > CAP; effectively never for this graph)
    for (int i2f = CAP + w; i2f < deg; i2f += 4) {
        int src = csr_src[s0 + i2f];
        float ev = 0.f;
        if (l < H) {
            float al = asrc[src * H + l] + adst_n;
            al = al >= 0.f ? al : 0.2f * al;
            ev = __expf(al);
        }
        const __bf16* hp = hb + (size_t)src * CH;
        float wgt = __shfl(ev, h0);
        bf16x8 hv = *(const bf16x8*)(hp + l * 8);
#pragma unroll
        for (int jj = 0; jj < 8; jj++) acc[jj] += (float)hv[jj] * wgt;
        if (H == 6) {
            float wg1 = __shfl(ev, h1i);
            bf16x4 hv1 = *(const bf16x4*)(hp + 512 + l * 4);
#pragma unroll
            for (int jj = 0; jj < 4; jj++) acc[8 + jj] += (float)hv1[jj] * wg1;
        }
    }

    *(f32x4*)(sm + w * CH + l * 8)     = *(f32x4*)(acc);
    *(f32x4*)(sm + w * CH + l * 8 + 4) = *(f32x4*)(acc + 4);
    if (H == 6)
        *(f32x4*)(sm + w * CH + 512 + l * 4) = *(f32x4*)(acc + 8);
    __syncthreads();

    float v = 0.f;
    if (t < 128) {
#pragma unroll
        for (int hh = 0; hh < H; hh++) {
            float hsum = 0.f;
#pragma unroll
            for (int ww = 0; ww < 4; ww++) hsum += sm[ww * CH + hh * 128 + t];
            v += hsum * invden[hh];
        }
        v = v * (1.f / H) + bias[t];
    }
    float sv = (t < 128) ? v : 0.f;
    float sq = (t < 128) ? v * v : 0.f;
#pragma unroll
    for (int off = 32; off; off >>= 1) {
        sv += __shfl_down(sv, off);
        sq += __shfl_down(sq, off);
    }
    if ((t & 63) == 0) { red[w * 2] = sv; red[w * 2 + 1] = sq; }
    __syncthreads();
    float tot = red[0] + red[2] + red[4] + red[6];
    float tsq = red[1] + red[3] + red[5] + red[7];
    float mu = tot * (1.f / 128.f);
    float var = tsq * (1.f / 128.f) - mu * mu;
    float r = rsqrtf(var + 1e-5f);
    if (t < 128) {
        float o = fmaxf((v - mu) * r * gamma[t] + beta[t], 0.f);
        // MFMA-A swizzled store: n -> (rt,r), t -> (p,off)
        int rt2 = n >> 6, rr = n & 63, pp = t >> 3, off2 = t & 7;
        outs[((size_t)(rt2 * 16 + pp) * 64 + rr) * 8 + off2] = (__bf16)o;
    }
}

// ---------------------------------------------------------------------------
// per-node GCN aggregation (round-15 vectorized): LPE lanes own 8 cols each
// (16B loads), G edge-groups in flight; LDS tree-reduce across groups.
// ---------------------------------------------------------------------------
template<int C>
__global__ void gcn_agg_kernel(const __bf16* __restrict__ y,
                               const float* __restrict__ dinv,
                               const int* __restrict__ rowstart,
                               const int* __restrict__ csr_src,
                               const float* __restrict__ bias,
                               float* __restrict__ out, int coloff,
                               __bf16* __restrict__ bout) {
    constexpr int LPE = C / 8;        // lanes per edge (16 or 8)
    constexpr int G = 128 / LPE;      // edge groups in flight (8 or 16)
    __shared__ float sm[G * C];       // 4 KB
    int n = blockIdx.x;
    int t = threadIdx.x;
    int lane = t & (LPE - 1);
    int grp = t / LPE;
    float acc[8] = {};
    int s0 = rowstart[n], s1 = rowstart[n + 1];
    for (int e = s0 + grp; e < s1; e += G) {
        int src = csr_src[e];
        float dv = dinv[src];
        bf16x8 v = *(const bf16x8*)(y + (size_t)src * C + lane * 8);
#pragma unroll
        for (int j = 0; j < 8; j++) acc[j] += (float)v[j] * dv;
    }
    *(f32x4*)(sm + grp * C + lane * 8)     = *(f32x4*)(acc);
    *(f32x4*)(sm + grp * C + lane * 8 + 4) = *(f32x4*)(acc + 4);
    __syncthreads();
    if (t < C) {
        float v = 0.f;
#pragma unroll
        for (int g = 0; g < G; g++) v += sm[g * C + t];
        v = fmaxf(v * dinv[n] + bias[t], 0.f);
        out[(size_t)n * 192 + coloff + t] = v;
        if (bout) {
            int rt = n >> 6, r = n & 63, p = t >> 3, off = t & 7;
            bout[((size_t)(rt * 16 + p) * 64 + r) * 8 + off] = (__bf16)v;
        }
    }
}

// ---------------------------------------------------------------------------
// Fused: fused=relu(cat@W_fuse+b_fuse); v=fused+relu(skippre+b_skip);
// LN(v) -> 64->32->16->5 MLP. (round-15: 16 nodes/block, verified)
// ---------------------------------------------------------------------------
__global__ __launch_bounds__(256)
void fuse_final_kernel(const float* __restrict__ cat,
                       const float* __restrict__ skippre,
                       const float* __restrict__ Wf, const float* __restrict__ bfz,
                       const float* __restrict__ b_skip,
                       const float* __restrict__ g3, const float* __restrict__ be3,
                       const float* __restrict__ Wc1, const float* __restrict__ bc1,
                       const float* __restrict__ Wc2, const float* __restrict__ bc2,
                       const float* __restrict__ Wc3, const float* __restrict__ bc3,
                       float* __restrict__ out) {
    __shared__ float WfS[192 * 64];     // 48 KB
    __shared__ float catS[4][4][196];   // 12.25 KB
    __shared__ float fS[4][64], h1S[4][32], h2S[4][16];
    int tid = threadIdx.x;
    int w = tid >> 6, l = tid & 63;
#pragma unroll
    for (int i = 0; i < 12; i++) {
        int idx = (i * 256 + tid) * 4;
        *(f32x4*)(WfS + idx) = *(const f32x4*)(Wf + idx);
    }
    int n0 = blockIdx.x * 16 + w * 4;
    float sk[4];
#pragma unroll
    for (int i = 0; i < 4; i++) {
        int n = n0 + i;
        if (n < NN) {
            catS[w][i][l]       = cat[(size_t)n * 192 + l];
            catS[w][i][64 + l]  = cat[(size_t)n * 192 + 64 + l];
            catS[w][i][128 + l] = cat[(size_t)n * 192 + 128 + l];
            sk[i] = fmaxf(skippre[(size_t)n * 64 + l] + b_skip[l], 0.f);
        } else {
            sk[i] = 0.f;
        }
    }
    __syncthreads();

#pragma unroll
    for (int i = 0; i < 4; i++) {
        int n = n0 + i;
        if (n < NN) {
            float fu = bfz[l];
#pragma unroll 4
            for (int k = 0; k < 192; k++)
                fu += catS[w][i][k] * WfS[k * 64 + l];
            float v = fmaxf(fu, 0.f) + sk[i];

            float sv = v, sq = v * v;
#pragma unroll
            for (int off = 32; off; off >>= 1) {
                sv += __shfl_xor(sv, off);
                sq += __shfl_xor(sq, off);
            }
            float mu = sv * (1.f / 64.f);
            float var = sq * (1.f / 64.f) - mu * mu;
            float r = rsqrtf(var + 1e-5f);
            fS[w][l] = (v - mu) * r * g3[l] + be3[l];
            // per-wave private LDS: no __syncthreads needed between stages
            if (l < 32) {
                float a = bc1[l];
                for (int k = 0; k < 64; k++) a += fS[w][k] * Wc1[k * 32 + l];
                h1S[w][l] = fmaxf(a, 0.f);
            }
            if (l < 16) {
                float a = bc2[l];
                for (int k = 0; k < 32; k++) a += h1S[w][k] * Wc2[k * 16 + l];
                h2S[w][l] = fmaxf(a, 0.f);
            }
            if (l < 5) {
                float a = bc3[l];
                for (int k = 0; k < 16; k++) a += h2S[w][k] * Wc3[k * 5 + l];
                out[(size_t)n * 5 + l] = a;
            }
        }
    }
}

// ---------------------------------------------------------------------------
extern "C" void kernel_launch(void* const* d_in, const int* in_sizes, int n_in,
                              void* d_out, int out_size, void* d_ws, size_t ws_size,
                              hipStream_t stream) {
    const float* x      = (const float*)d_in[0];
    const int*   ei     = (const int*)d_in[1];
    const float* W_gat1 = (const float*)d_in[2];
    const float* a_src1 = (const float*)d_in[3];
    const float* a_dst1 = (const float*)d_in[4];
    const float* b_gat1 = (const float*)d_in[5];
    const float* W_gcn1 = (const float*)d_in[6];
    const float* b_gcn1 = (const float*)d_in[7];
    const float* W_gat2 = (const float*)d_in[8];
    const float* a_src2 = (const float*)d_in[9];
    const float* a_dst2 = (const float*)d_in[10];
    const float* b_gat2 = (const float*)d_in[11];
    const float* W_gcn2 = (const float*)d_in[12];
    const float* b_gcn2 = (const float*)d_in[13];
    const float* W_skip = (const float*)d_in[14];
    const float* b_skip = (const float*)d_in[15];
    const float* W_fuse = (const float*)d_in[16];
    const float* b_fuse = (const float*)d_in[17];
    const float* W_c1   = (const float*)d_in[18];
    const float* b_c1   = (const float*)d_in[19];
    const float* W_c2   = (const float*)d_in[20];
    const float* b_c2   = (const float*)d_in[21];
    const float* W_c3   = (const float*)d_in[22];
    const float* b_c3   = (const float*)d_in[23];
    const float* g1     = (const float*)d_in[24];
    const float* be1    = (const float*)d_in[25];
    const float* g2     = (const float*)d_in[26];
    const float* be2    = (const float*)d_in[27];
    const float* g3     = (const float*)d_in[28];
    const float* be3    = (const float*)d_in[29];
    float* out = (float*)d_out;

    // workspace arena
    char* p = (char*)d_ws;
    auto alloc = [&](size_t bytes) {
        char* r = p; p += (bytes + 255) & ~(size_t)255; return r;
    };
    __bf16* xb      = (__bf16*)alloc((size_t)MPAD * KPAD * 2);   // 41.4 MB (swizzled)
    __bf16* wt      = (__bf16*)alloc((size_t)NPAD * KPAD * 2);   // 3.7 MB  (swizzled)
    __bf16* w2t     = (__bf16*)alloc((size_t)512 * 128 * 2);     // swizzled
    __bf16* wgcn1s  = (__bf16*)alloc((size_t)128 * 128 * 2);     // swizzled
    __bf16* wgcn2s  = (__bf16*)alloc((size_t)64 * 128 * 2);      // swizzled
    __bf16* h1b     = (__bf16*)alloc((size_t)NN * 768 * 2);      // 15.4 MB
    __bf16* h2b     = (__bf16*)alloc((size_t)NN * 512 * 2);      // 10.2 MB
    __bf16* ybufb   = (__bf16*)alloc((size_t)NN * 128 * 2);      // y1 reused y2
    // three swizzled activation buffers, contiguous for a single memset
    __bf16* x1gatb  = (__bf16*)alloc((size_t)3 * MPAD * 128 * 2);
    __bf16* x1gcnb  = x1gatb + (size_t)MPAD * 128;
    __bf16* x2gatb  = x1gcnb + (size_t)MPAD * 128;
    float* asrc     = (float*)alloc((size_t)NN * 6 * 4);
    float* adst     = (float*)alloc((size_t)NN * 6 * 4);
    int*   deg      = (int*)  alloc((size_t)2 * NN * 4);         // deg | cursor
    int*   cursor   = deg + NN;
    float* dinv     = (float*)alloc((size_t)NN * 4);
    int*   rowst    = (int*)  alloc((size_t)(NN + 1) * 4);
    int*   csrc     = (int*)  alloc((size_t)ET * 4);
    float* cat      = (float*)alloc((size_t)NN * 192 * 4);
    float* skippre  = (float*)alloc((size_t)NN * 64 * 4);

    hipMemsetAsync(deg, 0, (size_t)2 * NN * 4, stream);
    hipMemsetAsync(x1gatb, 0, (size_t)3 * MPAD * 128 * 2, stream);  // pad rows

    // merged conversions + degree count (round-19 load schedule)
    conv_kernel<<<NBX + WBLK + EB, 256, 0, stream>>>(
        x, xb, W_gat1, W_skip, W_gat2, W_gcn1, W_gcn2,
        wt, w2t, wgcn1s, wgcn2s, ei, deg);

    // CSR by dst
    scan_kernel   <<<1, 1024, 0, stream>>>(deg, rowst, dinv);
    scatter_kernel<<<EB, 256, 0, stream>>>(ei, rowst, cursor, csrc);

    // h1 (bf16) + skippre + fused alpha1, XCD-swizzled 128x128 BK=64, 8 waves
    // (round-11 verified structure, frozen)
    mfma_gemm1_kernel<<<560, 512, 0, stream>>>(xb, wt, a_src1, a_dst1,
                                               h1b, skippre, asrc, adst);

    // ---- GAT layer 1 (H=6) -> bf16 swizzled x1gatb ----
    gat_agg_kernel<6><<<NN, 256, 0, stream>>>(h1b, asrc, adst, rowst, csrc,
                                              b_gat1, g1, be1, x1gatb);
    // ---- GCN layer 1: y1 = x1gat @ W_gcn1 (MFMA) ----
    mfma_gcn_kernel<128><<<MPAD / 64, 256, 0, stream>>>(x1gatb, wgcn1s, ybufb);
    gcn_agg_kernel<128><<<NN, 128, 0, stream>>>(ybufb, dinv, rowst, csrc,
                                                b_gcn1, cat, 0, x1gcnb);
    // ---- GAT layer 2 (H=4): h2 + fused alpha2 (r7-verified 64x128/4-wave) ----
    mfma_gemm2_kernel<<<dim3(4, MPAD / 64), 256, 0, stream>>>(
        x1gcnb, w2t, a_src2, a_dst2, h2b, asrc, adst);
    gat_agg_kernel<4><<<NN, 256, 0, stream>>>(h2b, asrc, adst, rowst, csrc,
                                              b_gat2, g2, be2, x2gatb);
    // ---- GCN layer 2: y2 = x2gat @ W_gcn2 (MFMA) -> cat[:, 128:192] ----
    mfma_gcn_kernel<64><<<MPAD / 64, 256, 0, stream>>>(x2gatb, wgcn2s, ybufb);
    gcn_agg_kernel<64><<<NN, 128, 0, stream>>>(ybufb, dinv, rowst, csrc,
                                               b_gcn2, cat, 128, nullptr);
    // ---- fuse + final (round-15: 16 nodes/block) ----
    fuse_final_kernel<<<(NN + 15) / 16, 256, 0, stream>>>(
        cat, skippre, W_fuse, b_fuse, b_skip, g3, be3,
        W_c1, b_c1, W_c2, b_c2, W_c3, b_c3, out);
}

// Round 12
// 396.635 us; speedup vs baseline: 1.1032x; 1.0071x over previous
//
#include <hip/hip_runtime.h>
#include <cstdint>
#include <cstddef>

#define NN 10000
#define NE 160000
#define ET (NE + NN)          // edges + self loops
#define FIN 2000
#define MPAD 10112            // 158 * 64
#define KPAD 2048
#define NPAD 896              // 7 * 128 (768 gat1 cols + 64 skip + 64 pad)

typedef __bf16 bf16x8 __attribute__((ext_vector_type(8)));
typedef __bf16 bf16x4 __attribute__((ext_vector_type(4)));
typedef float  f32x4  __attribute__((ext_vector_type(4)));

#define GLL(src, dst) __builtin_amdgcn_global_load_lds( \
    (const __attribute__((address_space(1))) void*)(src), \
    (__attribute__((address_space(3))) void*)(dst), 16, 0, 0)

// ---------------------------------------------------------------------------
// CSR build
// ---------------------------------------------------------------------------
__device__ __forceinline__ void edge_sd(const int* ei, int e, int& s, int& d) {
    if (e < NE) { s = ei[e]; d = ei[NE + e]; }
    else        { s = e - NE; d = e - NE; }
}

// exclusive scan over deg -> rowstart[0..NN]; also dinv = deg^-1/2
// (round-16: 1024 threads)
__global__ __launch_bounds__(1024)
void scan_kernel(const int* deg, int* rowstart, float* dinv) {
    __shared__ int wsum[16];
    const int T = 1024;
    int chunk = (NN + T - 1) / T;        // 10
    int t = threadIdx.x;
    int begin = t * chunk;
    int end = begin + chunk; if (end > NN) end = NN;
    if (begin > NN) begin = NN;
    int s = 0;
    for (int i = begin; i < end; i++) s += deg[i];
    int inc = s;
#pragma unroll
    for (int off = 1; off < 64; off <<= 1) {
        int u = __shfl_up(inc, off);
        if ((t & 63) >= off) inc += u;
    }
    if ((t & 63) == 63) wsum[t >> 6] = inc;
    __syncthreads();
    int woff = 0;
    for (int wv = 0; wv < (t >> 6); wv++) woff += wsum[wv];
    int run = woff + inc - s;            // exclusive prefix for this thread
    for (int i = begin; i < end; i++) {
        rowstart[i] = run; run += deg[i];
        int dg = deg[i];
        dinv[i] = dg > 0 ? rsqrtf((float)dg) : 0.f;
    }
    if (end == NN) rowstart[NN] = run;
}

__global__ void scatter_kernel(const int* ei, const int* rowstart, int* cursor,
                               int* csr_src) {
    int e = blockIdx.x * blockDim.x + threadIdx.x;
    if (e >= ET) return;
    int s, d; edge_sd(ei, e, s, d);
    int pos = atomicAdd(&cursor[d], 1);
    csr_src[rowstart[d] + pos] = s;
}

// ---------------------------------------------------------------------------
// Merged conversion + degree count.
// Round-20 (resubmitted r11 after infra failure): xb branch stores DIRECTLY
// from registers — the LDS round-trip (stage + barrier + read-back) was only
// for write coalescing, but the direct pattern already merges to full 64B
// segments per wave (16 planes x 4 consecutive rows x 16B). Deletes 2 LDS
// ops/16B + 1 barrier + the 32KB LDS allocation.
// xb chunk c = ((rt*32 + ks)*8 + p)*64 + r holds x[rt*64+r][ks*64+p*8 ..+8)
// wt chunk: ((ct*32 + ks)*8 + p)*128 + r ; w2t chunk: (ct*16 + p)*128 + r
// wgcn1s chunk: p*128 + r (p 0..15) ; wgcn2s chunk: p*64 + r (p 0..15)
// ---------------------------------------------------------------------------
#define NBX (158 * 8)
#define NW1 (NPAD * KPAD / 8)                 // 229376
#define NWT (NW1 + 512 * 128 / 8)             // 237568
#define NWT2 (NWT + 2048 + 1024)              // + wgcn1s + wgcn2s
#define WBLK ((NWT2 + 255) / 256)
#define EB 665                                 // ceil(ET/256)
__global__ void conv_kernel(const float* __restrict__ x, __bf16* __restrict__ xb,
                            const float* __restrict__ Wg, const float* __restrict__ Ws,
                            const float* __restrict__ W2,
                            const float* __restrict__ Wg1, const float* __restrict__ Wg2,
                            __bf16* __restrict__ wt, __bf16* __restrict__ w2t,
                            __bf16* __restrict__ wgcn1s, __bf16* __restrict__ wgcn2s,
                            const int* __restrict__ ei, int* __restrict__ deg) {
    int bid = blockIdx.x;
    int tid = threadIdx.x;
    if (bid < NBX) {
        int rt = bid >> 3, kb = bid & 7;       // 64-row tile, 256-k tile
        const int lane16 = tid & 15;           // k-chunk owner within row
        const int ksl = lane16 >> 2;           // slab 0..3
        const int p0 = (lane16 & 3) * 2;       // p pair {p0, p0+1}
        const int rbase = tid >> 4;            // 0..15
        const int kg0 = kb * 256 + lane16 * 16;

        // phase A: issue all 16 loads (fully unrolled -> static reg indices)
        f32x4 f[16];
#pragma unroll
        for (int pass = 0; pass < 4; pass++) {
            int row = rt * 64 + pass * 16 + rbase;
            const float* xr = x + (size_t)row * FIN;
#pragma unroll
            for (int j = 0; j < 4; j++) {
                int k = kg0 + j * 4;
                if (row < NN && k + 3 < FIN)
                    f[pass * 4 + j] = *(const f32x4*)(xr + k);
                else
                    f[pass * 4 + j] = (f32x4){0.f, 0.f, 0.f, 0.f};
            }
        }
        // phase B: pack + DIRECT global stores (64B-segment coalesced:
        // lanes {l16, l16+16, l16+32, l16+48} cover 4 consecutive rows)
        size_t base = ((size_t)rt * 32 + kb * 4 + ksl) * 512;
#pragma unroll
        for (int pass = 0; pass < 4; pass++) {
            int r = pass * 16 + rbase;
            bf16x8 v0, v1;
#pragma unroll
            for (int j = 0; j < 4; j++) {
                f32x4 ff = f[pass * 4 + j];
                int o = (j & 1) * 4;
                if (j < 2) {
                    v0[o] = (__bf16)ff[0]; v0[o+1] = (__bf16)ff[1];
                    v0[o+2] = (__bf16)ff[2]; v0[o+3] = (__bf16)ff[3];
                } else {
                    v1[o] = (__bf16)ff[0]; v1[o+1] = (__bf16)ff[1];
                    v1[o+2] = (__bf16)ff[2]; v1[o+3] = (__bf16)ff[3];
                }
            }
            *(bf16x8*)(xb + (base + (size_t)p0 * 64 + r) * 8)       = v0;
            *(bf16x8*)(xb + (base + (size_t)(p0 + 1) * 64 + r) * 8) = v1;
        }
    } else if (bid < NBX + WBLK) {
        int g = (bid - NBX) * 256 + tid;
        if (g < NW1) {
            int r = g & 127, p = (g >> 7) & 7, ks = (g >> 10) & 31, ct = g >> 15;
            int n = ct * 128 + r;
            int k0 = ks * 64 + p * 8;
            bf16x8 o;
#pragma unroll
            for (int j = 0; j < 8; j++) {
                int k = k0 + j;
                float v = 0.f;
                if (k < FIN) {
                    if (n < 768)      v = Wg[(size_t)k * 768 + n];
                    else if (n < 832) v = Ws[(size_t)k * 64 + (n - 768)];
                }
                o[j] = (__bf16)v;
            }
            *(bf16x8*)(wt + (size_t)g * 8) = o;
        } else if (g < NWT) {
            int g2 = g - NW1;
            int c = g2 & 2047;
            int ct = g2 >> 11;
            int p = c >> 7, r = c & 127;
            int n = ct * 128 + r;
            int k0 = p * 8;
            bf16x8 o;
#pragma unroll
            for (int j = 0; j < 8; j++)
                o[j] = (__bf16)W2[(size_t)(k0 + j) * 512 + n];
            *(bf16x8*)(w2t + (size_t)g2 * 8) = o;
        } else if (g < NWT + 2048) {
            int g3 = g - NWT;
            int p = g3 >> 7, r = g3 & 127;
            bf16x8 o;
#pragma unroll
            for (int j = 0; j < 8; j++)
                o[j] = (__bf16)Wg1[(size_t)(p * 8 + j) * 128 + r];
            *(bf16x8*)(wgcn1s + (size_t)g3 * 8) = o;
        } else if (g < NWT2) {
            int g4 = g - NWT - 2048;
            int p = g4 >> 6, r = g4 & 63;
            bf16x8 o;
#pragma unroll
            for (int j = 0; j < 8; j++)
                o[j] = (__bf16)Wg2[(size_t)(p * 8 + j) * 64 + r];
            *(bf16x8*)(wgcn2s + (size_t)g4 * 8) = o;
        }
    } else {
        int e = (bid - NBX - WBLK) * 256 + tid;
        if (e < ET) {
            int s, d; edge_sd(ei, e, s, d);
            atomicAdd(&deg[d], 1);
        }
    }
}

// ---------------------------------------------------------------------------
// MFMA GEMM 1: xb @ wt^T -> h1b bf16[NN,768], skippre f32[NN,64], + fused
// alpha1. 128M x 128N block, 8 waves (32x64 each, 4x2), BK=64. 512 threads.
// (round-11 verified: ~57 us, MfmaUtil 26%, VGPR 40 — FROZEN.)
// ---------------------------------------------------------------------------
__global__ __launch_bounds__(512)
void mfma_gemm1_kernel(const __bf16* __restrict__ xb, const __bf16* __restrict__ wt,
                       const float* __restrict__ a_src1, const float* __restrict__ a_dst1,
                       __bf16* __restrict__ h1b, float* __restrict__ skippre,
                       float* __restrict__ asrc, float* __restrict__ adst) {
    __shared__ __bf16 As[8192];    // 8 planes x 128 rows x 8 (16 KB)
    __shared__ __bf16 Bs[8192];    // 8 planes x 128 rows x 8 (16 KB)
    __shared__ float sA[128], sD[128];
    __shared__ float asd[256];
    int b = blockIdx.x;
    int xcd = b & 7, j = b >> 3;
    int jq = j / 7;
    int rt = xcd + 8 * jq;            // same-rt blocks share an XCD (A-slab L2 reuse)
    int ct = j - 7 * jq;
    if (rt >= MPAD / 128) return;     // 79 row tiles
    const int bi = rt * 128;
    const int bn = ct * 128;

    const int tid = threadIdx.x;
    const int lane = tid & 63;
    const int w = tid >> 6;           // 0..7
    const int wm = w >> 1;            // 0..3 : 32-row band
    const int wn = w & 1;             // 0..1 : 64-col half
    const int q = lane >> 4, m16 = lane & 15;

    if (tid < 128) { sA[tid] = 0.f; sD[tid] = 0.f; }
    if (ct < 6) {
        if (tid < 128)      asd[tid] = a_src1[ct * 128 + tid];
        else if (tid < 256) asd[tid] = a_dst1[ct * 128 + (tid - 128)];
    }

    f32x4 acc[2][4] = {};

    for (int ks = 0; ks < KPAD / 64; ks++) {
        // A: two adjacent 64-row slabs (rt*2, rt*2+1); 16 segs = p*2 + h
        const size_t slabA = ((size_t)(rt * 2) * 32 + ks) * 512;
        const size_t slabB = ((size_t)ct * 32 + ks) * 1024;
#pragma unroll
        for (int i = 0; i < 2; i++) {
            int seg = i * 8 + w;              // 0..15
            int p = seg >> 1, h = seg & 1;
            GLL(xb + (slabA + (size_t)h * 16384 + p * 64 + lane) * 8,
                As + seg * 512);              // As[(p*128 + h*64 + r)*8]
        }
#pragma unroll
        for (int i = 0; i < 2; i++) {
            int seg = i * 8 + w;              // 0..15 = p*2 + half
            GLL(wt + (slabB + seg * 64 + lane) * 8, Bs + seg * 512);
        }
        __syncthreads();

#pragma unroll
        for (int kk = 0; kk < 2; kk++) {
            const int pb = kk * 4 + q;
            bf16x8 af[2], bfr[4];
#pragma unroll
            for (int mt = 0; mt < 2; mt++)
                af[mt] = *(const bf16x8*)(As + (pb * 128 + wm * 32 + mt * 16 + m16) * 8);
#pragma unroll
            for (int nt = 0; nt < 4; nt++)
                bfr[nt] = *(const bf16x8*)(Bs + (pb * 128 + wn * 64 + nt * 16 + m16) * 8);
#pragma unroll
            for (int mt = 0; mt < 2; mt++)
#pragma unroll
                for (int nt = 0; nt < 4; nt++)
                    acc[mt][nt] = __builtin_amdgcn_mfma_f32_16x16x32_bf16(af[mt], bfr[nt], acc[mt][nt], 0, 0, 0);
        }
        __syncthreads();
    }

#pragma unroll
    for (int mt = 0; mt < 2; mt++) {
#pragma unroll
        for (int r = 0; r < 4; r++) {
            int rowl = wm * 32 + mt * 16 + q * 4 + r;
            int row = bi + rowl;
            float ps = 0.f, pd = 0.f;
#pragma unroll
            for (int nt = 0; nt < 4; nt++) {
                int coll = wn * 64 + nt * 16 + m16;
                int col = bn + coll;
                float v = acc[mt][nt][r];
                if (ct < 6) { ps += v * asd[coll]; pd += v * asd[128 + coll]; }
                if (row < NN) {
                    if (col < 768)      h1b[(size_t)row * 768 + col] = (__bf16)v;
                    else if (col < 832) skippre[(size_t)row * 64 + (col - 768)] = v;
                }
            }
            if (ct < 6) {
#pragma unroll
                for (int off = 1; off < 16; off <<= 1) {
                    ps += __shfl_xor(ps, off);
                    pd += __shfl_xor(pd, off);
                }
                if (m16 == 0) { atomicAdd(&sA[rowl], ps); atomicAdd(&sD[rowl], pd); }
            }
        }
    }
    if (ct < 6) {
        __syncthreads();
        if (tid < 128) {
            int row = bi + tid;
            if (row < NN) { asrc[row * 6 + ct] = sA[tid]; adst[row * 6 + ct] = sD[tid]; }
        }
    }
}

// ---------------------------------------------------------------------------
// MFMA GEMM 2: x1gcnb(swizzled)[MPAD,128] @ w2t(swizzled)[512,128]^T -> h2b
// bf16[NN,512], + fused alpha2. 64x128 block, 4 waves (32x64), BK=64, 256 thr.
// (round-7 verified config — FROZEN.)
// ---------------------------------------------------------------------------
__global__ __launch_bounds__(256)
void mfma_gemm2_kernel(const __bf16* __restrict__ A, const __bf16* __restrict__ B,
                       const float* __restrict__ a_src2, const float* __restrict__ a_dst2,
                       __bf16* __restrict__ h2b,
                       float* __restrict__ asrc, float* __restrict__ adst) {
    __shared__ __bf16 As[4096];
    __shared__ __bf16 Bs[8192];
    __shared__ float sA[64], sD[64];
    __shared__ float asd[256];
    const int rt = blockIdx.y, ct = blockIdx.x;
    const int bi = rt * 64, bn = ct * 128;
    const int tid = threadIdx.x, lane = tid & 63, w = tid >> 6;
    const int wm = w >> 1, wn = w & 1;
    const int q = lane >> 4, m16 = lane & 15;

    if (tid < 64) { sA[tid] = 0.f; sD[tid] = 0.f; }
    if (tid < 128) asd[tid] = a_src2[ct * 128 + tid];
    else           asd[tid] = a_dst2[ct * 128 + (tid - 128)];

    f32x4 acc[2][4] = {};

    for (int ks = 0; ks < 2; ks++) {
        const size_t slabA = (size_t)rt * 1024 + ks * 512;
        const size_t slabB = (size_t)ct * 2048 + ks * 1024;
#pragma unroll
        for (int i = 0; i < 2; i++) {
            int seg = i * 4 + w;
            GLL(A + (slabA + seg * 64 + lane) * 8, As + seg * 512);
        }
#pragma unroll
        for (int i = 0; i < 4; i++) {
            int seg = i * 4 + w;
            GLL(B + (slabB + seg * 64 + lane) * 8, Bs + seg * 512);
        }
        __syncthreads();

#pragma unroll
        for (int kk = 0; kk < 2; kk++) {
            const int pb = kk * 4 + q;
            bf16x8 af[2], bfr[4];
#pragma unroll
            for (int mt = 0; mt < 2; mt++)
                af[mt] = *(const bf16x8*)(As + (pb * 64 + wm * 32 + mt * 16 + m16) * 8);
#pragma unroll
            for (int nt = 0; nt < 4; nt++)
                bfr[nt] = *(const bf16x8*)(Bs + (pb * 128 + wn * 64 + nt * 16 + m16) * 8);
#pragma unroll
            for (int mt = 0; mt < 2; mt++)
#pragma unroll
                for (int nt = 0; nt < 4; nt++)
                    acc[mt][nt] = __builtin_amdgcn_mfma_f32_16x16x32_bf16(af[mt], bfr[nt], acc[mt][nt], 0, 0, 0);
        }
        __syncthreads();
    }

#pragma unroll
    for (int mt = 0; mt < 2; mt++) {
#pragma unroll
        for (int r = 0; r < 4; r++) {
            int rowl = wm * 32 + mt * 16 + q * 4 + r;
            int row = bi + rowl;
            float ps = 0.f, pd = 0.f;
#pragma unroll
            for (int nt = 0; nt < 4; nt++) {
                int coll = wn * 64 + nt * 16 + m16;
                float v = acc[mt][nt][r];
                ps += v * asd[coll]; pd += v * asd[128 + coll];
                if (row < NN) h2b[(size_t)row * 512 + bn + coll] = (__bf16)v;
            }
#pragma unroll
            for (int off = 1; off < 16; off <<= 1) {
                ps += __shfl_xor(ps, off);
                pd += __shfl_xor(pd, off);
            }
            if (m16 == 0) { atomicAdd(&sA[rowl], ps); atomicAdd(&sD[rowl], pd); }
        }
    }
    __syncthreads();
    if (tid < 64) {
        int row = bi + tid;
        if (row < NN) { asrc[row * 4 + ct] = sA[tid]; adst[row * 4 + ct] = sD[tid]; }
    }
}

// ---------------------------------------------------------------------------
// MFMA GCN GEMM: A(swizzled)[MPAD,128] @ Bs(swizzled)[NT,128]^T -> y bf16[NN,NT]
// 64M x NT block, 4 waves, BK=64 (2 iters), 256 threads. NT in {64,128}.
// ---------------------------------------------------------------------------
template<int NT>
__global__ __launch_bounds__(256)
void mfma_gcn_kernel(const __bf16* __restrict__ A, const __bf16* __restrict__ B,
                     __bf16* __restrict__ Cb) {
    __shared__ __bf16 As[4096];
    __shared__ __bf16 Bs[NT * 64];      // 8 planes x NT rows x 8
    const int rt = blockIdx.x;
    const int bi = rt * 64;
    const int tid = threadIdx.x, lane = tid & 63, w = tid >> 6;
    const int q = lane >> 4, m16 = lane & 15;
    constexpr int MT = (NT == 128) ? 2 : 1;
    constexpr int MSPAN = (NT == 128) ? 32 : 16;
    const int wm = (NT == 128) ? (w >> 1) : w;
    const int wn = (NT == 128) ? (w & 1) : 0;

    f32x4 acc[MT][4] = {};

    for (int ks = 0; ks < 2; ks++) {
        const size_t slabA = (size_t)rt * 1024 + ks * 512;
        const size_t slabB = (size_t)ks * (NT * 8);
#pragma unroll
        for (int i = 0; i < 2; i++) {
            int seg = i * 4 + w;
            GLL(A + (slabA + seg * 64 + lane) * 8, As + seg * 512);
        }
#pragma unroll
        for (int i = 0; i < NT / 32; i++) {
            int seg = i * 4 + w;
            GLL(B + (slabB + (size_t)seg * 64 + lane) * 8, Bs + seg * 512);
        }
        __syncthreads();

#pragma unroll
        for (int kk = 0; kk < 2; kk++) {
            const int pb = kk * 4 + q;
            bf16x8 af[MT], bfr[4];
#pragma unroll
            for (int mt = 0; mt < MT; mt++)
                af[mt] = *(const bf16x8*)(As + (pb * 64 + wm * MSPAN + mt * 16 + m16) * 8);
#pragma unroll
            for (int nt = 0; nt < 4; nt++)
                bfr[nt] = *(const bf16x8*)(Bs + (pb * NT + wn * 64 + nt * 16 + m16) * 8);
#pragma unroll
            for (int mt = 0; mt < MT; mt++)
#pragma unroll
                for (int nt = 0; nt < 4; nt++)
                    acc[mt][nt] = __builtin_amdgcn_mfma_f32_16x16x32_bf16(af[mt], bfr[nt], acc[mt][nt], 0, 0, 0);
        }
        __syncthreads();
    }

#pragma unroll
    for (int mt = 0; mt < MT; mt++) {
#pragma unroll
        for (int r = 0; r < 4; r++) {
            int row = bi + wm * MSPAN + mt * 16 + q * 4 + r;
            if (row >= NN) continue;
#pragma unroll
            for (int nt = 0; nt < 4; nt++) {
                int col = wn * 64 + nt * 16 + m16;
                Cb[(size_t)row * NT + col] = (__bf16)acc[mt][nt][r];
            }
        }
    }
}

// ---------------------------------------------------------------------------
// Fused segment-softmax + aggregation + head-mean + bias + LN + ReLU.
// T14 async prefetch, 4 edges/wave deep (r8/r9/r10-verified).
// ---------------------------------------------------------------------------
template<int H>
__global__ void gat_agg_kernel(const __bf16* __restrict__ hb,
                               const float* __restrict__ asrc,
                               const float* __restrict__ adst,
                               const int* __restrict__ rowstart,
                               const int* __restrict__ csr_src,
                               const float* __restrict__ bias,
                               const float* __restrict__ gamma,
                               const float* __restrict__ beta,
                               __bf16* __restrict__ outs) {
    constexpr int CH = H * 128;
    constexpr int CAP = 128;
    int n = blockIdx.x;
    int t = threadIdx.x;
    int w = t >> 6, l = t & 63;
    __shared__ float invden[H];
    __shared__ float denp[256];
    __shared__ int   srcs[CAP];
    __shared__ float evs[CAP * H];
    __shared__ float sm[4 * CH];
    __shared__ float red[8];

    int s0 = rowstart[n];
    int deg = rowstart[n + 1] - s0;
    int degc = deg < CAP ? deg : CAP;
    float adst_n = (l < H) ? adst[n * H + l] : 0.f;   // for fallback path

    // phase 0: cooperative srcs load
    if (t < degc) srcs[t] = csr_src[s0 + t];
    __syncthreads();

    // prologue (T14): issue this wave's first FOUR h-row gathers now — they
    // depend only on srcs, so their latency overlaps all of phase 1.
    const int h0 = l >> 4;
    const int h1i = 4 + (l >> 5);
    const int i0 = w, i1 = w + 4, i2 = w + 8, i3 = w + 12;
    const bool has0 = i0 < degc, has1 = i1 < degc;
    const bool has2 = i2 < degc, has3 = i3 < degc;
    bf16x8 pg0, pg1, pg2, pg3; bf16x4 pe0, pe1, pe2, pe3;
    if (has0) {
        const __bf16* hp = hb + (size_t)srcs[i0] * CH;
        pg0 = *(const bf16x8*)(hp + l * 8);
        if (H == 6) pe0 = *(const bf16x4*)(hp + 512 + l * 4);
    }
    if (has1) {
        const __bf16* hp = hb + (size_t)srcs[i1] * CH;
        pg1 = *(const bf16x8*)(hp + l * 8);
        if (H == 6) pe1 = *(const bf16x4*)(hp + 512 + l * 4);
    }
    if (has2) {
        const __bf16* hp = hb + (size_t)srcs[i2] * CH;
        pg2 = *(const bf16x8*)(hp + l * 8);
        if (H == 6) pe2 = *(const bf16x4*)(hp + 512 + l * 4);
    }
    if (has3) {
        const __bf16* hp = hb + (size_t)srcs[i3] * CH;
        pg3 = *(const bf16x8*)(hp + l * 8);
        if (H == 6) pe3 = *(const bf16x4*)(hp + 512 + l * 4);
    }

    // phase 1: parallel over (edge, head): 8 lanes per edge, 32 edges/pass
    const int eh = t >> 3;      // edge slot within pass (0..31)
    const int hh1 = t & 7;      // head (hh1 < H active)
    float adst_h = (hh1 < H) ? adst[n * H + hh1] : 0.f;
    float dloc = 0.f;
    for (int base = 0; base < deg; base += 32) {
        int idx = base + eh;
        if (idx < deg && hh1 < H) {
            int src = (idx < CAP) ? srcs[idx] : csr_src[s0 + idx];
            float al = asrc[src * H + hh1] + adst_h;
            al = al >= 0.f ? al : 0.2f * al;
            float ev = __expf(al);
            dloc += ev;
            if (idx < CAP) evs[idx * H + hh1] = ev;
        }
    }
    denp[t] = dloc;
    __syncthreads();
    if (t < H) {
        float s = 0.f;
#pragma unroll
        for (int g = 0; g < 32; g++) s += denp[g * 8 + t];
        invden[t] = 1.f / s;
    }
    __syncthreads();

    // phase 2: weighted feature accumulation
    constexpr int NA = (H == 6) ? 12 : 8;
    float acc[NA] = {};
    // consume the preloaded edges (weights now available in evs)
    if (has0) {
        float w0 = evs[i0 * H + h0];
#pragma unroll
        for (int jj = 0; jj < 8; jj++) acc[jj] += (float)pg0[jj] * w0;
        if (H == 6) {
            float w1 = evs[i0 * H + h1i];
#pragma unroll
            for (int jj = 0; jj < 4; jj++) acc[8 + jj] += (float)pe0[jj] * w1;
        }
    }
    if (has1) {
        float w0 = evs[i1 * H + h0];
#pragma unroll
        for (int jj = 0; jj < 8; jj++) acc[jj] += (float)pg1[jj] * w0;
        if (H == 6) {
            float w1 = evs[i1 * H + h1i];
#pragma unroll
            for (int jj = 0; jj < 4; jj++) acc[8 + jj] += (float)pe1[jj] * w1;
        }
    }
    if (has2) {
        float w0 = evs[i2 * H + h0];
#pragma unroll
        for (int jj = 0; jj < 8; jj++) acc[jj] += (float)pg2[jj] * w0;
        if (H == 6) {
            float w1 = evs[i2 * H + h1i];
#pragma unroll
            for (int jj = 0; jj < 4; jj++) acc[8 + jj] += (float)pe2[jj] * w1;
        }
    }
    if (has3) {
        float w0 = evs[i3 * H + h0];
#pragma unroll
        for (int jj = 0; jj < 8; jj++) acc[jj] += (float)pg3[jj] * w0;
        if (H == 6) {
            float w1 = evs[i3 * H + h1i];
#pragma unroll
            for (int jj = 0; jj < 4; jj++) acc[8 + jj] += (float)pe3[jj] * w1;
        }
    }
    // remaining edges from w+16, 2-edge pipelined
    int idx = w + 16;
    for (; idx + 4 < degc; idx += 8) {
        int src0 = srcs[idx], src1 = srcs[idx + 4];
        float w00 = evs[idx * H + h0];
        float w10 = evs[(idx + 4) * H + h0];
        const __bf16* hp0 = hb + (size_t)src0 * CH;
        const __bf16* hp1 = hb + (size_t)src1 * CH;
        bf16x8 g00 = *(const bf16x8*)(hp0 + l * 8);
        bf16x8 g10 = *(const bf16x8*)(hp1 + l * 8);
#pragma unroll
        for (int jj = 0; jj < 8; jj++)
            acc[jj] += (float)g00[jj] * w00 + (float)g10[jj] * w10;
        if (H == 6) {
            float w01 = evs[idx * H + h1i];
            float w11 = evs[(idx + 4) * H + h1i];
            bf16x4 g01 = *(const bf16x4*)(hp0 + 512 + l * 4);
            bf16x4 g11 = *(const bf16x4*)(hp1 + 512 + l * 4);
#pragma unroll
            for (int jj = 0; jj < 4; jj++)
                acc[8 + jj] += (float)g01[jj] * w01 + (float)g11[jj] * w11;
        }
    }
    if (idx < degc) {
        int src = srcs[idx];
        float w0 = evs[idx * H + h0];
        const __bf16* hp = hb + (size_t)src * CH;
        bf16x8 hv = *(const bf16x8*)(hp + l * 8);
#pragma unroll
        for (int jj = 0; jj < 8; jj++) acc[jj] += (float)hv[jj] * w0;
        if (H == 6) {
            float w1 = evs[idx * H + h1i];
            bf16x4 hv1 = *(const bf16x4*)(hp + 512 + l * 4);
#pragma unroll
            for (int jj = 0; jj < 4; jj++) acc[8 + jj] += (float)hv1[jj] * w1;
        }
    }
    // fallback: uncached edges (deg > CAP; effectively never for this graph)
    for (int i2f = CAP + w; i2f < deg; i2f += 4) {
        int src = csr_src[s0 + i2f];
        float ev = 0.f;
        if (l < H) {
            float al = asrc[src * H + l] + adst_n;
            al = al >= 0.f ? al : 0.2f * al;
            ev = __expf(al);
        }
        const __bf16* hp = hb + (size_t)src * CH;
        float wgt = __shfl(ev, h0);
        bf16x8 hv = *(const bf16x8*)(hp + l * 8);
#pragma unroll
        for (int jj = 0; jj < 8; jj++) acc[jj] += (float)hv[jj] * wgt;
        if (H == 6) {
            float wg1 = __shfl(ev, h1i);
            bf16x4 hv1 = *(const bf16x4*)(hp + 512 + l * 4);
#pragma unroll
            for (int jj = 0; jj < 4; jj++) acc[8 + jj] += (float)hv1[jj] * wg1;
        }
    }

    *(f32x4*)(sm + w * CH + l * 8)     = *(f32x4*)(acc);
    *(f32x4*)(sm + w * CH + l * 8 + 4) = *(f32x4*)(acc + 4);
    if (H == 6)
        *(f32x4*)(sm + w * CH + 512 + l * 4) = *(f32x4*)(acc + 8);
    __syncthreads();

    float v = 0.f;
    if (t < 128) {
#pragma unroll
        for (int hh = 0; hh < H; hh++) {
            float hsum = 0.f;
#pragma unroll
            for (int ww = 0; ww < 4; ww++) hsum += sm[ww * CH + hh * 128 + t];
            v += hsum * invden[hh];
        }
        v = v * (1.f / H) + bias[t];
    }
    float sv = (t < 128) ? v : 0.f;
    float sq = (t < 128) ? v * v : 0.f;
#pragma unroll
    for (int off = 32; off; off >>= 1) {
        sv += __shfl_down(sv, off);
        sq += __shfl_down(sq, off);
    }
    if ((t & 63) == 0) { red[w * 2] = sv; red[w * 2 + 1] = sq; }
    __syncthreads();
    float tot = red[0] + red[2] + red[4] + red[6];
    float tsq = red[1] + red[3] + red[5] + red[7];
    float mu = tot * (1.f / 128.f);
    float var = tsq * (1.f / 128.f) - mu * mu;
    float r = rsqrtf(var + 1e-5f);
    if (t < 128) {
        float o = fmaxf((v - mu) * r * gamma[t] + beta[t], 0.f);
        // MFMA-A swizzled store: n -> (rt,r), t -> (p,off)
        int rt2 = n >> 6, rr = n & 63, pp = t >> 3, off2 = t & 7;
        outs[((size_t)(rt2 * 16 + pp) * 64 + rr) * 8 + off2] = (__bf16)o;
    }
}

// ---------------------------------------------------------------------------
// per-node GCN aggregation (round-15 vectorized): LPE lanes own 8 cols each
// (16B loads), G edge-groups in flight; LDS tree-reduce across groups.
// ---------------------------------------------------------------------------
template<int C>
__global__ void gcn_agg_kernel(const __bf16* __restrict__ y,
                               const float* __restrict__ dinv,
                               const int* __restrict__ rowstart,
                               const int* __restrict__ csr_src,
                               const float* __restrict__ bias,
                               float* __restrict__ out, int coloff,
                               __bf16* __restrict__ bout) {
    constexpr int LPE = C / 8;        // lanes per edge (16 or 8)
    constexpr int G = 128 / LPE;      // edge groups in flight (8 or 16)
    __shared__ float sm[G * C];       // 4 KB
    int n = blockIdx.x;
    int t = threadIdx.x;
    int lane = t & (LPE - 1);
    int grp = t / LPE;
    float acc[8] = {};
    int s0 = rowstart[n], s1 = rowstart[n + 1];
    for (int e = s0 + grp; e < s1; e += G) {
        int src = csr_src[e];
        float dv = dinv[src];
        bf16x8 v = *(const bf16x8*)(y + (size_t)src * C + lane * 8);
#pragma unroll
        for (int j = 0; j < 8; j++) acc[j] += (float)v[j] * dv;
    }
    *(f32x4*)(sm + grp * C + lane * 8)     = *(f32x4*)(acc);
    *(f32x4*)(sm + grp * C + lane * 8 + 4) = *(f32x4*)(acc + 4);
    __syncthreads();
    if (t < C) {
        float v = 0.f;
#pragma unroll
        for (int g = 0; g < G; g++) v += sm[g * C + t];
        v = fmaxf(v * dinv[n] + bias[t], 0.f);
        out[(size_t)n * 192 + coloff + t] = v;
        if (bout) {
            int rt = n >> 6, r = n & 63, p = t >> 3, off = t & 7;
            bout[((size_t)(rt * 16 + p) * 64 + r) * 8 + off] = (__bf16)v;
        }
    }
}

// ---------------------------------------------------------------------------
// Fused: fused=relu(cat@W_fuse+b_fuse); v=fused+relu(skippre+b_skip);
// LN(v) -> 64->32->16->5 MLP. (round-15: 16 nodes/block, verified)
// ---------------------------------------------------------------------------
__global__ __launch_bounds__(256)
void fuse_final_kernel(const float* __restrict__ cat,
                       const float* __restrict__ skippre,
                       const float* __restrict__ Wf, const float* __restrict__ bfz,
                       const float* __restrict__ b_skip,
                       const float* __restrict__ g3, const float* __restrict__ be3,
                       const float* __restrict__ Wc1, const float* __restrict__ bc1,
                       const float* __restrict__ Wc2, const float* __restrict__ bc2,
                       const float* __restrict__ Wc3, const float* __restrict__ bc3,
                       float* __restrict__ out) {
    __shared__ float WfS[192 * 64];     // 48 KB
    __shared__ float catS[4][4][196];   // 12.25 KB
    __shared__ float fS[4][64], h1S[4][32], h2S[4][16];
    int tid = threadIdx.x;
    int w = tid >> 6, l = tid & 63;
#pragma unroll
    for (int i = 0; i < 12; i++) {
        int idx = (i * 256 + tid) * 4;
        *(f32x4*)(WfS + idx) = *(const f32x4*)(Wf + idx);
    }
    int n0 = blockIdx.x * 16 + w * 4;
    float sk[4];
#pragma unroll
    for (int i = 0; i < 4; i++) {
        int n = n0 + i;
        if (n < NN) {
            catS[w][i][l]       = cat[(size_t)n * 192 + l];
            catS[w][i][64 + l]  = cat[(size_t)n * 192 + 64 + l];
            catS[w][i][128 + l] = cat[(size_t)n * 192 + 128 + l];
            sk[i] = fmaxf(skippre[(size_t)n * 64 + l] + b_skip[l], 0.f);
        } else {
            sk[i] = 0.f;
        }
    }
    __syncthreads();

#pragma unroll
    for (int i = 0; i < 4; i++) {
        int n = n0 + i;
        if (n < NN) {
            float fu = bfz[l];
#pragma unroll 4
            for (int k = 0; k < 192; k++)
                fu += catS[w][i][k] * WfS[k * 64 + l];
            float v = fmaxf(fu, 0.f) + sk[i];

            float sv = v, sq = v * v;
#pragma unroll
            for (int off = 32; off; off >>= 1) {
                sv += __shfl_xor(sv, off);
                sq += __shfl_xor(sq, off);
            }
            float mu = sv * (1.f / 64.f);
            float var = sq * (1.f / 64.f) - mu * mu;
            float r = rsqrtf(var + 1e-5f);
            fS[w][l] = (v - mu) * r * g3[l] + be3[l];
            // per-wave private LDS: no __syncthreads needed between stages
            if (l < 32) {
                float a = bc1[l];
                for (int k = 0; k < 64; k++) a += fS[w][k] * Wc1[k * 32 + l];
                h1S[w][l] = fmaxf(a, 0.f);
            }
            if (l < 16) {
                float a = bc2[l];
                for (int k = 0; k < 32; k++) a += h1S[w][k] * Wc2[k * 16 + l];
                h2S[w][l] = fmaxf(a, 0.f);
            }
            if (l < 5) {
                float a = bc3[l];
                for (int k = 0; k < 16; k++) a += h2S[w][k] * Wc3[k * 5 + l];
                out[(size_t)n * 5 + l] = a;
            }
        }
    }
}

// ---------------------------------------------------------------------------
extern "C" void kernel_launch(void* const* d_in, const int* in_sizes, int n_in,
                              void* d_out, int out_size, void* d_ws, size_t ws_size,
                              hipStream_t stream) {
    const float* x      = (const float*)d_in[0];
    const int*   ei     = (const int*)d_in[1];
    const float* W_gat1 = (const float*)d_in[2];
    const float* a_src1 = (const float*)d_in[3];
    const float* a_dst1 = (const float*)d_in[4];
    const float* b_gat1 = (const float*)d_in[5];
    const float* W_gcn1 = (const float*)d_in[6];
    const float* b_gcn1 = (const float*)d_in[7];
    const float* W_gat2 = (const float*)d_in[8];
    const float* a_src2 = (const float*)d_in[9];
    const float* a_dst2 = (const float*)d_in[10];
    const float* b_gat2 = (const float*)d_in[11];
    const float* W_gcn2 = (const float*)d_in[12];
    const float* b_gcn2 = (const float*)d_in[13];
    const float* W_skip = (const float*)d_in[14];
    const float* b_skip = (const float*)d_in[15];
    const float* W_fuse = (const float*)d_in[16];
    const float* b_fuse = (const float*)d_in[17];
    const float* W_c1   = (const float*)d_in[18];
    const float* b_c1   = (const float*)d_in[19];
    const float* W_c2   = (const float*)d_in[20];
    const float* b_c2   = (const float*)d_in[21];
    const float* W_c3   = (const float*)d_in[22];
    const float* b_c3   = (const float*)d_in[23];
    const float* g1     = (const float*)d_in[24];
    const float* be1    = (const float*)d_in[25];
    const float* g2     = (const float*)d_in[26];
    const float* be2    = (const float*)d_in[27];
    const float* g3     = (const float*)d_in[28];
    const float* be3    = (const float*)d_in[29];
    float* out = (float*)d_out;

    // workspace arena
    char* p = (char*)d_ws;
    auto alloc = [&](size_t bytes) {
        char* r = p; p += (bytes + 255) & ~(size_t)255; return r;
    };
    __bf16* xb      = (__bf16*)alloc((size_t)MPAD * KPAD * 2);   // 41.4 MB (swizzled)
    __bf16* wt      = (__bf16*)alloc((size_t)NPAD * KPAD * 2);   // 3.7 MB  (swizzled)
    __bf16* w2t     = (__bf16*)alloc((size_t)512 * 128 * 2);     // swizzled
    __bf16* wgcn1s  = (__bf16*)alloc((size_t)128 * 128 * 2);     // swizzled
    __bf16* wgcn2s  = (__bf16*)alloc((size_t)64 * 128 * 2);      // swizzled
    __bf16* h1b     = (__bf16*)alloc((size_t)NN * 768 * 2);      // 15.4 MB
    __bf16* h2b     = (__bf16*)alloc((size_t)NN * 512 * 2);      // 10.2 MB
    __bf16* ybufb   = (__bf16*)alloc((size_t)NN * 128 * 2);      // y1 reused y2
    // three swizzled activation buffers, contiguous for a single memset
    __bf16* x1gatb  = (__bf16*)alloc((size_t)3 * MPAD * 128 * 2);
    __bf16* x1gcnb  = x1gatb + (size_t)MPAD * 128;
    __bf16* x2gatb  = x1gcnb + (size_t)MPAD * 128;
    float* asrc     = (float*)alloc((size_t)NN * 6 * 4);
    float* adst     = (float*)alloc((size_t)NN * 6 * 4);
    int*   deg      = (int*)  alloc((size_t)2 * NN * 4);         // deg | cursor
    int*   cursor   = deg + NN;
    float* dinv     = (float*)alloc((size_t)NN * 4);
    int*   rowst    = (int*)  alloc((size_t)(NN + 1) * 4);
    int*   csrc     = (int*)  alloc((size_t)ET * 4);
    float* cat      = (float*)alloc((size_t)NN * 192 * 4);
    float* skippre  = (float*)alloc((size_t)NN * 64 * 4);

    hipMemsetAsync(deg, 0, (size_t)2 * NN * 4, stream);
    hipMemsetAsync(x1gatb, 0, (size_t)3 * MPAD * 128 * 2, stream);  // pad rows

    // merged conversions + degree count (round-20: direct-store xb, no LDS)
    conv_kernel<<<NBX + WBLK + EB, 256, 0, stream>>>(
        x, xb, W_gat1, W_skip, W_gat2, W_gcn1, W_gcn2,
        wt, w2t, wgcn1s, wgcn2s, ei, deg);

    // CSR by dst
    scan_kernel   <<<1, 1024, 0, stream>>>(deg, rowst, dinv);
    scatter_kernel<<<EB, 256, 0, stream>>>(ei, rowst, cursor, csrc);

    // h1 (bf16) + skippre + fused alpha1, XCD-swizzled 128x128 BK=64, 8 waves
    // (round-11 verified structure, frozen)
    mfma_gemm1_kernel<<<560, 512, 0, stream>>>(xb, wt, a_src1, a_dst1,
                                               h1b, skippre, asrc, adst);

    // ---- GAT layer 1 (H=6) -> bf16 swizzled x1gatb ----
    gat_agg_kernel<6><<<NN, 256, 0, stream>>>(h1b, asrc, adst, rowst, csrc,
                                              b_gat1, g1, be1, x1gatb);
    // ---- GCN layer 1: y1 = x1gat @ W_gcn1 (MFMA) ----
    mfma_gcn_kernel<128><<<MPAD / 64, 256, 0, stream>>>(x1gatb, wgcn1s, ybufb);
    gcn_agg_kernel<128><<<NN, 128, 0, stream>>>(ybufb, dinv, rowst, csrc,
                                                b_gcn1, cat, 0, x1gcnb);
    // ---- GAT layer 2 (H=4): h2 + fused alpha2 (r7-verified 64x128/4-wave) ----
    mfma_gemm2_kernel<<<dim3(4, MPAD / 64), 256, 0, stream>>>(
        x1gcnb, w2t, a_src2, a_dst2, h2b, asrc, adst);
    gat_agg_kernel<4><<<NN, 256, 0, stream>>>(h2b, asrc, adst, rowst, csrc,
                                              b_gat2, g2, be2, x2gatb);
    // ---- GCN layer 2: y2 = x2gat @ W_gcn2 (MFMA) -> cat[:, 128:192] ----
    mfma_gcn_kernel<64><<<MPAD / 64, 256, 0, stream>>>(x2gatb, wgcn2s, ybufb);
    gcn_agg_kernel<64><<<NN, 128, 0, stream>>>(ybufb, dinv, rowst, csrc,
                                               b_gcn2, cat, 128, nullptr);
    // ---- fuse + final (round-15: 16 nodes/block) ----
    fuse_final_kernel<<<(NN + 15) / 16, 256, 0, stream>>>(
        cat, skippre, W_fuse, b_fuse, b_skip, g3, be3,
        W_c1, b_c1, W_c2, b_c2, W_c3, b_c3, out);
}